// Round 4
// baseline (27750.903 us; speedup 1.0000x reference)
//
#include <hip/hip_runtime.h>
#include <hip/hip_cooperative_groups.h>
#include <stdint.h>

typedef uint32_t u32;

#define DEV static __device__ __forceinline__

#define BATCH 512
#define CD    64
#define ZL    16
#define HID   512
#define H2D   256
#define NC    9
#define SLEN  64
#define L1    35
#define KCAT  288   /* 274 padded to 9*32 */

#define JAX_PARTITIONABLE 1

// ---------------- Threefry-2x32 (JAX key schedule, 20 rounds) ----------------
DEV void threefry2x32(u32 k0, u32 k1, u32 x0, u32 x1, u32 &o0, u32 &o1){
  const u32 ks2 = k0 ^ k1 ^ 0x1BD11BDAu;
#define TF_R(d) { x0 += x1; x1 = (x1 << (d)) | (x1 >> (32 - (d))); x1 ^= x0; }
  x0 += k0; x1 += k1;
  TF_R(13) TF_R(15) TF_R(26) TF_R(6)
  x0 += k1;  x1 += ks2 + 1u;
  TF_R(17) TF_R(29) TF_R(16) TF_R(24)
  x0 += ks2; x1 += k0 + 2u;
  TF_R(13) TF_R(15) TF_R(26) TF_R(6)
  x0 += k0;  x1 += k1 + 3u;
  TF_R(17) TF_R(29) TF_R(16) TF_R(24)
  x0 += k1;  x1 += ks2 + 4u;
  TF_R(13) TF_R(15) TF_R(26) TF_R(6)
  x0 += ks2; x1 += k0 + 5u;
#undef TF_R
  o0 = x0; o1 = x1;
}

DEV void step_key(int t, u32 &ka, u32 &kb){
#if JAX_PARTITIONABLE
  threefry2x32(0u, 42u, 0u, (u32)t, ka, kb);
#else
  u32 j0 = 2u*(u32)t, j1 = j0 + 1u, a0, a1;
  if (j0 < 64u){ threefry2x32(0u,42u, j0, 64u+j0, a0, a1); ka = a0; }
  else         { threefry2x32(0u,42u, j0-64u, j0, a0, a1); ka = a1; }
  if (j1 < 64u){ threefry2x32(0u,42u, j1, 64u+j1, a0, a1); kb = a0; }
  else         { threefry2x32(0u,42u, j1-64u, j1, a0, a1); kb = a1; }
#endif
}

DEV float rng_uniform(u32 ka, u32 kb, u32 f){
  u32 bits, o0, o1;
#if JAX_PARTITIONABLE
  threefry2x32(ka, kb, 0u, f, o0, o1);
  bits = o0 ^ o1;
#else
  const u32 HALF = (u32)(BATCH * NC / 2);
  if (f < HALF){ threefry2x32(ka, kb, f, f + HALF, o0, o1); bits = o0; }
  else         { threefry2x32(ka, kb, f - HALF, f, o0, o1); bits = o1; }
#endif
  u32 fb = (bits >> 9) | 0x3F800000u;
  float fv; __builtin_memcpy(&fv, &fb, 4);
  return fv - 1.0f;
}

// ---------------- ConvT1 (64->512, k=4, s=2, opad=1) + BN + LReLU ----------------
__global__ __launch_bounds__(256) void k_conv1(
    const float* __restrict__ z, const float* __restrict__ w1, const float* __restrict__ b1,
    const float* __restrict__ g1, const float* __restrict__ bt1, const float* __restrict__ m1,
    const float* __restrict__ v1, float* __restrict__ y1out)
{
  int t = blockIdx.x;
  int bg = blockIdx.y * 8;
  int tid = threadIdx.x;
  __shared__ float zsh[2][8][CD];
  int k0 = t & 1;
  int sA = (t - k0) >> 1, sB = sA - 1;
  bool vA = (sA >= 0 && sA < ZL), vB = (sB >= 0 && sB < ZL);
  for (int l = tid; l < 2*8*CD; l += 256){
    int p = l >> 9, bb = (l >> 6) & 7, i = l & 63;
    int s = p ? sB : sA; bool v = p ? vB : vA;
    zsh[p][bb][i] = v ? z[((bg + bb)*CD + i)*ZL + s] : 0.f;
  }
  __syncthreads();
  const float4* w1v = (const float4*)w1;
  for (int o = tid; o < HID; o += 256){
    float acc[8] = {0,0,0,0,0,0,0,0};
    for (int i = 0; i < CD; i++){
      float4 wv = w1v[i*HID + o];
      float wA = k0 ? wv.y : wv.x;
      float wB = k0 ? wv.w : wv.z;
      #pragma unroll
      for (int bb = 0; bb < 8; bb++)
        acc[bb] += zsh[0][bb][i]*wA + zsh[1][bb][i]*wB;
    }
    float xb = b1[o];
    float sc = g1[o] / sqrtf(v1[o] + 1e-5f);
    float mm = m1[o], be = bt1[o];
    #pragma unroll
    for (int bb = 0; bb < 8; bb++){
      float y = (acc[bb] + xb - mm)*sc + be;
      y = (y > 0.f) ? y : 0.2f*y;
      y1out[((bg + bb)*L1 + t)*HID + o] = y;
    }
  }
}

// ---------------- ConvT2 (512->256, k=4, s=2) + BN + LReLU -> xinT[t][c][b] ------
__global__ __launch_bounds__(256) void k_conv2(
    const float* __restrict__ y1, const float* __restrict__ w2, const float* __restrict__ b2,
    const float* __restrict__ g2, const float* __restrict__ bt2, const float* __restrict__ m2,
    const float* __restrict__ v2, float* __restrict__ xinT)
{
  int t = blockIdx.x;
  int bg = blockIdx.y * 8;
  int tid = threadIdx.x;
  __shared__ float ysh[2][8][HID];
  int k0 = t & 1;
  int sA = (t - k0) >> 1, sB = sA - 1;
  bool vB = (sB >= 0);
  for (int l = tid; l < 2*8*HID; l += 256){
    int p = l >> 12, bb = (l >> 9) & 7, o = l & 511;
    int s = p ? sB : sA; bool v = p ? vB : true;
    ysh[p][bb][o] = v ? y1[((bg + bb)*L1 + s)*HID + o] : 0.f;
  }
  __syncthreads();
  int c = tid;
  float acc[8] = {0,0,0,0,0,0,0,0};
  const float4* w2v = (const float4*)w2;
  for (int o4 = 0; o4 < HID; o4 += 4){
    float wA[4], wB[4];
    #pragma unroll
    for (int j = 0; j < 4; j++){
      float4 wv = w2v[(o4 + j)*H2D + c];
      wA[j] = k0 ? wv.y : wv.x;
      wB[j] = k0 ? wv.w : wv.z;
    }
    #pragma unroll
    for (int bb = 0; bb < 8; bb++){
      const float4 ya = *(const float4*)&ysh[0][bb][o4];
      const float4 yb = *(const float4*)&ysh[1][bb][o4];
      acc[bb] += ya.x*wA[0] + ya.y*wA[1] + ya.z*wA[2] + ya.w*wA[3]
               + yb.x*wB[0] + yb.y*wB[1] + yb.z*wB[2] + yb.w*wB[3];
    }
  }
  float xb = b2[c];
  float sc = g2[c] / sqrtf(v2[c] + 1e-5f);
  float mm = m2[c], be = bt2[c];
  float res[8];
  #pragma unroll
  for (int bb = 0; bb < 8; bb++){
    float y = (acc[bb] + xb - mm)*sc + be;
    res[bb] = (y > 0.f) ? y : 0.2f*y;
  }
  size_t base = (size_t)(t*H2D + c)*512 + bg;
  *(float4*)&xinT[base]     = make_float4(res[0],res[1],res[2],res[3]);
  *(float4*)&xinT[base + 4] = make_float4(res[4],res[5],res[6],res[7]);
}

// ---------------- h1_0 (transposed write h1T[n][b]) ------------------------------
__global__ __launch_bounds__(256) void k_h0(
    const float* __restrict__ se, const float* __restrict__ w, const float* __restrict__ bias,
    float* __restrict__ h1T)
{
  int b = blockIdx.x, tid = threadIdx.x;
  __shared__ float ssh[HID];
  for (int i = tid; i < HID; i += 256) ssh[i] = se[b*HID + i];
  __syncthreads();
  for (int j = tid; j < HID; j += 256){
    float acc = 0.f;
    for (int q = 0; q < HID; q++) acc += ssh[q] * w[j*HID + q];
    h1T[(size_t)j*512 + b] = acc + bias[j];
  }
}

// ---------------- prep: k-major transposed weights + skelT ------------------------
// wih1T[288][1536] (zero-pad k>=274), whh1T/wih2T/whh2T [512][1536], skelT[t][c][b]
__global__ __launch_bounds__(256) void k_prep(
    const float* __restrict__ wih1, const float* __restrict__ whh1,
    const float* __restrict__ wih2, const float* __restrict__ whh2,
    const float* __restrict__ skel,
    float* __restrict__ wih1T, float* __restrict__ whh1T,
    float* __restrict__ wih2T, float* __restrict__ whh2T,
    float* __restrict__ skelT)
{
  const int NTOT = KCAT*1536 + 3*512*1536 + SLEN*NC*512;
  for (int i = blockIdx.x*256 + threadIdx.x; i < NTOT; i += gridDim.x*256){
    int r = i;
    if (r < KCAT*1536){
      int k = r / 1536, n = r - k*1536;
      wih1T[r] = (k < 274) ? wih1[(size_t)n*274 + k] : 0.f;
      continue;
    }
    r -= KCAT*1536;
    if (r < 512*1536){
      int k = r / 1536, n = r - k*1536;
      whh1T[r] = whh1[(size_t)n*512 + k];
      continue;
    }
    r -= 512*1536;
    if (r < 512*1536){
      int k = r / 1536, n = r - k*1536;
      wih2T[r] = wih2[(size_t)n*512 + k];
      continue;
    }
    r -= 512*1536;
    if (r < 512*1536){
      int k = r / 1536, n = r - k*1536;
      whh2T[r] = whh2[(size_t)n*512 + k];
      continue;
    }
    r -= 512*1536;
    { // skelT
      int b = r & 511, q = r >> 9;
      int c = q % NC, tt = q / NC;
      skelT[r] = skel[((size_t)b*SLEN + tt)*NC + c];
    }
  }
}

// ---------------- persistent recurrence kernel ------------------------------------
// grid 256 x 256thr. nt=blockIdx&31 (16 hcols), bg=blockIdx>>5 (64 batch).
// wave = 64 lanes = 64 batch rows, handles 4 hcols x 3 gates.
// Weights: wave-uniform scalar loads from k-major W (s_load_dwordx4 x3 per k).
// A: ds_read_b128 per 4k per wave from [kq][b][4] tiles (16B lane stride, conflict-free).
__global__ __launch_bounds__(256, 1) void k_persist(
    const float* __restrict__ xinT, const float* __restrict__ skelT,
    const float* __restrict__ wih1T, const float* __restrict__ whh1T,
    const float* __restrict__ wih2T, const float* __restrict__ whh2T,
    const float* __restrict__ bih1,  const float* __restrict__ bhh1,
    const float* __restrict__ bih2,  const float* __restrict__ bhh2,
    const float* __restrict__ nw,    const float* __restrict__ nbias,
    float* __restrict__ h1a, float* __restrict__ h1b,
    float* __restrict__ h2a, float* __restrict__ h2b,
    float* __restrict__ dout)
{
  cooperative_groups::grid_group grid = cooperative_groups::this_grid();
  const int tid  = threadIdx.x;
  const int lane = tid & 63;
  const int wv   = __builtin_amdgcn_readfirstlane(tid >> 6);
  const int nt   = blockIdx.x & 31;
  const int bg   = blockIdx.x >> 5;
  const int b0   = bg * 64;
  const int bglob= b0 + lane;
  const int n0w  = nt*16 + wv*4;      // wave's 4 hcols base (uniform)

  __shared__ float A_lds[2][8][64][4];   // [buf][kq][b][k%4]  = 16 KB
  __shared__ float out_sh[NC][64];       // sampled feedback [c][b]
  __shared__ float h2_sh[32][64];        // logits staging [n][b]

  int t = 0;
  const float *h1prev, *h2prevB, *h2samp;
  float *h1new, *h2new;

  // ---- stage chunk (32 k) of an [k][512b] global matrix into A_lds[buf] ----
  auto stage_h = [&](int buf, const float* H, int kc){
    #pragma unroll
    for (int it = 0; it < 2; it++){
      int kq = (tid >> 6) + it*4;
      float v[4];
      #pragma unroll
      for (int j = 0; j < 4; j++)
        v[j] = H[(size_t)(kc + kq*4 + j)*512 + bglob];
      *(float4*)&A_lds[buf][kq][lane][0] = make_float4(v[0],v[1],v[2],v[3]);
    }
  };
  auto stage_cat = [&](int buf, int kc){
    #pragma unroll
    for (int it = 0; it < 2; it++){
      int kq = (tid >> 6) + it*4;
      float v[4];
      #pragma unroll
      for (int j = 0; j < 4; j++){
        int kg = kc + kq*4 + j;
        float x;
        if (kg < 9)        x = out_sh[kg][lane];
        else if (kg < 265) x = xinT[(size_t)(t*H2D + (kg-9))*512 + bglob];
        else if (kg < 274) x = skelT[(size_t)(t*NC + (kg-265))*512 + bglob];
        else               x = 0.f;
        v[j] = x;
      }
      *(float4*)&A_lds[buf][kq][lane][0] = make_float4(v[0],v[1],v[2],v[3]);
    }
  };
  // ---- compute chunk: 32 k, weights via uniform scalar loads ----
  auto gemm_chunk = [&](int buf, const float* Wt, int kc,
                        float* aR, float* aZ, float* aN){
    #pragma unroll
    for (int kq = 0; kq < 8; kq++){
      float4 a4 = *(const float4*)&A_lds[buf][kq][lane][0];
      const float av[4] = {a4.x, a4.y, a4.z, a4.w};
      #pragma unroll
      for (int j = 0; j < 4; j++){
        const float* wk = Wt + (size_t)(kc + kq*4 + j)*1536 + n0w;
        float a = av[j];
        #pragma unroll
        for (int h = 0; h < 4; h++) aR[h] += wk[h]        * a;
        #pragma unroll
        for (int h = 0; h < 4; h++) aZ[h] += wk[512 + h]  * a;
        #pragma unroll
        for (int h = 0; h < 4; h++) aN[h] += wk[1024 + h] * a;
      }
    }
  };
  // ---- double-buffered GEMM over NCH chunks; MODE: 0=cat source, 1=h source ----
  auto run_gemm = [&](int NCH, int mode, const float* H, const float* Wt,
                      float* aR, float* aZ, float* aN){
    if (mode == 0) stage_cat(0, 0); else stage_h(0, H, 0);
    __syncthreads();
    for (int c = 0; c < NCH; c++){
      if (c + 1 < NCH){
        if (mode == 0) stage_cat((c+1)&1, (c+1)*32);
        else           stage_h((c+1)&1, H, (c+1)*32);
      }
      gemm_chunk(c&1, Wt, c*32, aR, aZ, aN);
      __syncthreads();
    }
  };

  auto sample = [&](){
    if (t == 0){
      for (int idx = tid; idx < NC*64; idx += 256) out_sh[idx >> 6][idx & 63] = 0.f;
      __syncthreads();
      return;
    }
    float lacc[3] = {0.f, 0.f, 0.f};
    for (int nc = 0; nc < 512; nc += 32){
      #pragma unroll
      for (int j = 0; j < 8; j++){
        int e = j*256 + tid;
        h2_sh[e >> 6][e & 63] = h2samp[(size_t)(nc + (e >> 6))*512 + b0 + (e & 63)];
      }
      __syncthreads();
      int slot = 0;
      for (int idx = tid; idx < 576; idx += 256, slot++){
        int c = idx >> 6, bl = idx & 63;
        const float* wr = nw + c*512 + nc;
        float s = lacc[slot];
        #pragma unroll 8
        for (int nn = 0; nn < 32; nn++) s += h2_sh[nn][bl]*wr[nn];
        lacc[slot] = s;
      }
      __syncthreads();
    }
    int slot = 0;
    for (int idx = tid; idx < 576; idx += 256, slot++){
      int c = idx >> 6, bl = idx & 63;
      float logit = lacc[slot] + nbias[c];
      if (nt == 0) dout[((size_t)(b0 + bl)*SLEN + (t-1))*NC + c] = logit;
      if (t <= 63){
        u32 ka, kb2; step_key(t-1, ka, kb2);
        float r = rng_uniform(ka, kb2, (u32)((b0 + bl)*NC + c));
        float sg = 1.f/(1.f + expf(-logit));
        out_sh[c][bl] = (sg - r > 0.f) ? 1.f : 0.f;
      }
    }
    __syncthreads();
  };

  for (t = 0; t <= 64; t++){
    h1prev  = (t & 1) ? h1b : h1a;
    h1new   = (t & 1) ? h1a : h1b;
    h2new   = (t & 1) ? h2b : h2a;
    h2prevB = (t == 0) ? h1new : ((t & 1) ? h2a : h2b);
    h2samp  = ((t-1) & 1) ? h2b : h2a;

    sample();
    if (t == 64) break;

    // ---- GRU1: aR/aZ accumulate ih+hh; aI = ih n-gate; aH = hh n-gate ----
    float aR[4] = {0,0,0,0}, aZ[4] = {0,0,0,0}, aI[4] = {0,0,0,0}, aH[4] = {0,0,0,0};
    run_gemm(KCAT/32, 0, nullptr, wih1T, aR, aZ, aI);
    run_gemm(16,      1, h1prev,  whh1T, aR, aZ, aH);
    #pragma unroll
    for (int h = 0; h < 4; h++){
      int n = n0w + h;
      float r  = 1.f/(1.f + expf(-(aR[h] + bih1[n] + bhh1[n])));
      float z  = 1.f/(1.f + expf(-(aZ[h] + bih1[512+n] + bhh1[512+n])));
      float nn = tanhf(aI[h] + bih1[1024+n] + r*(aH[h] + bhh1[1024+n]));
      float hp = h1prev[(size_t)n*512 + bglob];
      h1new[(size_t)n*512 + bglob] = (1.f - z)*nn + z*hp;
    }
    grid.sync();

    // ---- GRU2 ----
    float cR[4] = {0,0,0,0}, cZ[4] = {0,0,0,0}, cI[4] = {0,0,0,0}, cH[4] = {0,0,0,0};
    run_gemm(16, 1, h1new,   wih2T, cR, cZ, cI);
    run_gemm(16, 1, h2prevB, whh2T, cR, cZ, cH);
    #pragma unroll
    for (int h = 0; h < 4; h++){
      int n = n0w + h;
      float r  = 1.f/(1.f + expf(-(cR[h] + bih2[n] + bhh2[n])));
      float z  = 1.f/(1.f + expf(-(cZ[h] + bih2[512+n] + bhh2[512+n])));
      float nn = tanhf(cI[h] + bih2[1024+n] + r*(cH[h] + bhh2[1024+n]));
      float hp = h2prevB[(size_t)n*512 + bglob];
      h2new[(size_t)n*512 + bglob] = (1.f - z)*nn + z*hp;
    }
    grid.sync();
  }
}

// ---------------- host ----------------
extern "C" void kernel_launch(void* const* d_in, const int* in_sizes, int n_in,
                              void* d_out, int out_size, void* d_ws, size_t ws_size,
                              hipStream_t stream) {
  (void)in_sizes; (void)n_in; (void)out_size; (void)ws_size;
  const float* z       = (const float*)d_in[0];
  const float* skel    = (const float*)d_in[2];
  const float* se      = (const float*)d_in[3];
  const float* ct1_w   = (const float*)d_in[6];
  const float* ct1_b   = (const float*)d_in[7];
  const float* bn1_g   = (const float*)d_in[8];
  const float* bn1_b   = (const float*)d_in[9];
  const float* bn1_m   = (const float*)d_in[10];
  const float* bn1_v   = (const float*)d_in[11];
  const float* ct2_w   = (const float*)d_in[12];
  const float* ct2_b   = (const float*)d_in[13];
  const float* bn2_g   = (const float*)d_in[14];
  const float* bn2_b   = (const float*)d_in[15];
  const float* bn2_m   = (const float*)d_in[16];
  const float* bn2_v   = (const float*)d_in[17];
  const float* hfc_w   = (const float*)d_in[18];
  const float* hfc_b   = (const float*)d_in[19];
  const float* g1_wih  = (const float*)d_in[20];
  const float* g1_whh  = (const float*)d_in[21];
  const float* g1_bih  = (const float*)d_in[22];
  const float* g1_bhh  = (const float*)d_in[23];
  const float* g2_wih  = (const float*)d_in[24];
  const float* g2_whh  = (const float*)d_in[25];
  const float* g2_bih  = (const float*)d_in[26];
  const float* g2_bhh  = (const float*)d_in[27];
  const float* nfc_w   = (const float*)d_in[28];
  const float* nfc_b   = (const float*)d_in[29];

  float* ws = (float*)d_ws;
  // conv phase:
  float* y1   = ws;                        // [0, 9,175,040) floats
  float* xinT = ws + 9175040;              // 64*256*512 = 8,388,608
  // recurrence phase — aliased into the dead y1 region (written after conv2):
  float* wih1T = ws;                       // 288*1536   = 442,368
  float* whh1T = ws + 442368;              // 512*1536   = 786,432
  float* wih2T = ws + 1228800;             // 786,432
  float* whh2T = ws + 2015232;             // 786,432
  float* skelT = ws + 2801664;             // 64*9*512   = 294,912
  float* h1a   = ws + 3096576;             // 262,144 each
  float* h1b   = ws + 3358720;
  float* h2a   = ws + 3620864;
  float* h2b   = ws + 3883008;             // ends 4,145,152 < 9,175,040 ok
  float* dout  = (float*)d_out;

  k_conv1<<<dim3(L1, BATCH/8), 256, 0, stream>>>(z, ct1_w, ct1_b, bn1_g, bn1_b, bn1_m, bn1_v, y1);
  k_conv2<<<dim3(SLEN, BATCH/8), 256, 0, stream>>>(y1, ct2_w, ct2_b, bn2_g, bn2_b, bn2_m, bn2_v, xinT);
  k_prep<<<2048, 256, 0, stream>>>(g1_wih, g1_whh, g2_wih, g2_whh, skel,
                                   wih1T, whh1T, wih2T, whh2T, skelT);
  k_h0<<<BATCH, 256, 0, stream>>>(se, hfc_w, hfc_b, h1a);

  void* args[] = {
    (void*)&xinT, (void*)&skelT, (void*)&wih1T, (void*)&whh1T,
    (void*)&wih2T, (void*)&whh2T, (void*)&g1_bih, (void*)&g1_bhh,
    (void*)&g2_bih, (void*)&g2_bhh, (void*)&nfc_w, (void*)&nfc_b,
    (void*)&h1a, (void*)&h1b, (void*)&h2a, (void*)&h2b, (void*)&dout
  };
  hipLaunchCooperativeKernel((const void*)k_persist, dim3(256), dim3(256), args, 0, stream);
}

// Round 5
// 18430.150 us; speedup vs baseline: 1.5057x; 1.5057x over previous
//
#include <hip/hip_runtime.h>
#include <hip/hip_cooperative_groups.h>
#include <stdint.h>

typedef uint32_t u32;

#define DEV static __device__ __forceinline__

#define BATCH 512
#define CD    64
#define ZL    16
#define HID   512
#define H2D   256
#define NC    9
#define SLEN  64
#define L1    35
#define KCAT  288   /* 274 padded to 9*32 */

#define JAX_PARTITIONABLE 1

// ---------------- Threefry-2x32 (JAX key schedule, 20 rounds) ----------------
DEV void threefry2x32(u32 k0, u32 k1, u32 x0, u32 x1, u32 &o0, u32 &o1){
  const u32 ks2 = k0 ^ k1 ^ 0x1BD11BDAu;
#define TF_R(d) { x0 += x1; x1 = (x1 << (d)) | (x1 >> (32 - (d))); x1 ^= x0; }
  x0 += k0; x1 += k1;
  TF_R(13) TF_R(15) TF_R(26) TF_R(6)
  x0 += k1;  x1 += ks2 + 1u;
  TF_R(17) TF_R(29) TF_R(16) TF_R(24)
  x0 += ks2; x1 += k0 + 2u;
  TF_R(13) TF_R(15) TF_R(26) TF_R(6)
  x0 += k0;  x1 += k1 + 3u;
  TF_R(17) TF_R(29) TF_R(16) TF_R(24)
  x0 += k1;  x1 += ks2 + 4u;
  TF_R(13) TF_R(15) TF_R(26) TF_R(6)
  x0 += ks2; x1 += k0 + 5u;
#undef TF_R
  o0 = x0; o1 = x1;
}

DEV void step_key(int t, u32 &ka, u32 &kb){
#if JAX_PARTITIONABLE
  threefry2x32(0u, 42u, 0u, (u32)t, ka, kb);
#else
  u32 j0 = 2u*(u32)t, j1 = j0 + 1u, a0, a1;
  if (j0 < 64u){ threefry2x32(0u,42u, j0, 64u+j0, a0, a1); ka = a0; }
  else         { threefry2x32(0u,42u, j0-64u, j0, a0, a1); ka = a1; }
  if (j1 < 64u){ threefry2x32(0u,42u, j1, 64u+j1, a0, a1); kb = a0; }
  else         { threefry2x32(0u,42u, j1-64u, j1, a0, a1); kb = a1; }
#endif
}

DEV float rng_uniform(u32 ka, u32 kb, u32 f){
  u32 bits, o0, o1;
#if JAX_PARTITIONABLE
  threefry2x32(ka, kb, 0u, f, o0, o1);
  bits = o0 ^ o1;
#else
  const u32 HALF = (u32)(BATCH * NC / 2);
  if (f < HALF){ threefry2x32(ka, kb, f, f + HALF, o0, o1); bits = o0; }
  else         { threefry2x32(ka, kb, f - HALF, f, o0, o1); bits = o1; }
#endif
  u32 fb = (bits >> 9) | 0x3F800000u;
  float fv; __builtin_memcpy(&fv, &fb, 4);
  return fv - 1.0f;
}

// ---------------- ConvT1 (64->512, k=4, s=2, opad=1) + BN + LReLU ----------------
__global__ __launch_bounds__(256) void k_conv1(
    const float* __restrict__ z, const float* __restrict__ w1, const float* __restrict__ b1,
    const float* __restrict__ g1, const float* __restrict__ bt1, const float* __restrict__ m1,
    const float* __restrict__ v1, float* __restrict__ y1out)
{
  int t = blockIdx.x;
  int bg = blockIdx.y * 8;
  int tid = threadIdx.x;
  __shared__ float zsh[2][8][CD];
  int k0 = t & 1;
  int sA = (t - k0) >> 1, sB = sA - 1;
  bool vA = (sA >= 0 && sA < ZL), vB = (sB >= 0 && sB < ZL);
  for (int l = tid; l < 2*8*CD; l += 256){
    int p = l >> 9, bb = (l >> 6) & 7, i = l & 63;
    int s = p ? sB : sA; bool v = p ? vB : vA;
    zsh[p][bb][i] = v ? z[((bg + bb)*CD + i)*ZL + s] : 0.f;
  }
  __syncthreads();
  const float4* w1v = (const float4*)w1;
  for (int o = tid; o < HID; o += 256){
    float acc[8] = {0,0,0,0,0,0,0,0};
    for (int i = 0; i < CD; i++){
      float4 wv = w1v[i*HID + o];
      float wA = k0 ? wv.y : wv.x;
      float wB = k0 ? wv.w : wv.z;
      #pragma unroll
      for (int bb = 0; bb < 8; bb++)
        acc[bb] += zsh[0][bb][i]*wA + zsh[1][bb][i]*wB;
    }
    float xb = b1[o];
    float sc = g1[o] / sqrtf(v1[o] + 1e-5f);
    float mm = m1[o], be = bt1[o];
    #pragma unroll
    for (int bb = 0; bb < 8; bb++){
      float y = (acc[bb] + xb - mm)*sc + be;
      y = (y > 0.f) ? y : 0.2f*y;
      y1out[((bg + bb)*L1 + t)*HID + o] = y;
    }
  }
}

// ---------------- ConvT2 (512->256, k=4, s=2) + BN + LReLU -> xinT[t][c][b] ------
__global__ __launch_bounds__(256) void k_conv2(
    const float* __restrict__ y1, const float* __restrict__ w2, const float* __restrict__ b2,
    const float* __restrict__ g2, const float* __restrict__ bt2, const float* __restrict__ m2,
    const float* __restrict__ v2, float* __restrict__ xinT)
{
  int t = blockIdx.x;
  int bg = blockIdx.y * 8;
  int tid = threadIdx.x;
  __shared__ float ysh[2][8][HID];
  int k0 = t & 1;
  int sA = (t - k0) >> 1, sB = sA - 1;
  bool vB = (sB >= 0);
  for (int l = tid; l < 2*8*HID; l += 256){
    int p = l >> 12, bb = (l >> 9) & 7, o = l & 511;
    int s = p ? sB : sA; bool v = p ? vB : true;
    ysh[p][bb][o] = v ? y1[((bg + bb)*L1 + s)*HID + o] : 0.f;
  }
  __syncthreads();
  int c = tid;
  float acc[8] = {0,0,0,0,0,0,0,0};
  const float4* w2v = (const float4*)w2;
  for (int o4 = 0; o4 < HID; o4 += 4){
    float wA[4], wB[4];
    #pragma unroll
    for (int j = 0; j < 4; j++){
      float4 wv = w2v[(o4 + j)*H2D + c];
      wA[j] = k0 ? wv.y : wv.x;
      wB[j] = k0 ? wv.w : wv.z;
    }
    #pragma unroll
    for (int bb = 0; bb < 8; bb++){
      const float4 ya = *(const float4*)&ysh[0][bb][o4];
      const float4 yb = *(const float4*)&ysh[1][bb][o4];
      acc[bb] += ya.x*wA[0] + ya.y*wA[1] + ya.z*wA[2] + ya.w*wA[3]
               + yb.x*wB[0] + yb.y*wB[1] + yb.z*wB[2] + yb.w*wB[3];
    }
  }
  float xb = b2[c];
  float sc = g2[c] / sqrtf(v2[c] + 1e-5f);
  float mm = m2[c], be = bt2[c];
  float res[8];
  #pragma unroll
  for (int bb = 0; bb < 8; bb++){
    float y = (acc[bb] + xb - mm)*sc + be;
    res[bb] = (y > 0.f) ? y : 0.2f*y;
  }
  size_t base = (size_t)(t*H2D + c)*512 + bg;
  *(float4*)&xinT[base]     = make_float4(res[0],res[1],res[2],res[3]);
  *(float4*)&xinT[base + 4] = make_float4(res[4],res[5],res[6],res[7]);
}

// ---------------- h1_0 (transposed write h1T[n][b]) ------------------------------
__global__ __launch_bounds__(256) void k_h0(
    const float* __restrict__ se, const float* __restrict__ w, const float* __restrict__ bias,
    float* __restrict__ h1T)
{
  int b = blockIdx.x, tid = threadIdx.x;
  __shared__ float ssh[HID];
  for (int i = tid; i < HID; i += 256) ssh[i] = se[b*HID + i];
  __syncthreads();
  for (int j = tid; j < HID; j += 256){
    float acc = 0.f;
    for (int q = 0; q < HID; q++) acc += ssh[q] * w[j*HID + q];
    h1T[(size_t)j*512 + b] = acc + bias[j];
  }
}

// ---------------- prep: k-major transposed weights + skelT ------------------------
__global__ __launch_bounds__(256) void k_prep(
    const float* __restrict__ wih1, const float* __restrict__ whh1,
    const float* __restrict__ wih2, const float* __restrict__ whh2,
    const float* __restrict__ skel,
    float* __restrict__ wih1T, float* __restrict__ whh1T,
    float* __restrict__ wih2T, float* __restrict__ whh2T,
    float* __restrict__ skelT)
{
  const int NTOT = KCAT*1536 + 3*512*1536 + SLEN*NC*512;
  for (int i = blockIdx.x*256 + threadIdx.x; i < NTOT; i += gridDim.x*256){
    int r = i;
    if (r < KCAT*1536){
      int k = r / 1536, n = r - k*1536;
      wih1T[r] = (k < 274) ? wih1[(size_t)n*274 + k] : 0.f;
      continue;
    }
    r -= KCAT*1536;
    if (r < 512*1536){
      int k = r / 1536, n = r - k*1536;
      whh1T[r] = whh1[(size_t)n*512 + k];
      continue;
    }
    r -= 512*1536;
    if (r < 512*1536){
      int k = r / 1536, n = r - k*1536;
      wih2T[r] = wih2[(size_t)n*512 + k];
      continue;
    }
    r -= 512*1536;
    if (r < 512*1536){
      int k = r / 1536, n = r - k*1536;
      whh2T[r] = whh2[(size_t)n*512 + k];
      continue;
    }
    r -= 512*1536;
    {
      int b = r & 511, q = r >> 9;
      int c = q % NC, tt = q / NC;
      skelT[r] = skel[((size_t)b*SLEN + tt)*NC + c];
    }
  }
}

// ---------------- persistent recurrence kernel ------------------------------------
// grid 256 x 512thr (8 waves). nt=blockIdx&31 (16 hcols), bg=blockIdx>>5 (64 batch).
// wave = 64 lanes = 64 batch rows, 4 hcols x 3 gates. half = K-split (waves 0-3 vs 4-7).
// Weights: uniform-address VMEM dwordx4 (mbcnt trick), 2-deep register pipeline.
__global__ __launch_bounds__(512, 2) void k_persist(
    const float* __restrict__ xinT, const float* __restrict__ skelT,
    const float* __restrict__ wih1T, const float* __restrict__ whh1T,
    const float* __restrict__ wih2T, const float* __restrict__ whh2T,
    const float* __restrict__ bih1,  const float* __restrict__ bhh1,
    const float* __restrict__ bih2,  const float* __restrict__ bhh2,
    const float* __restrict__ nw,    const float* __restrict__ nbias,
    float* __restrict__ h1a, float* __restrict__ h1b,
    float* __restrict__ h2a, float* __restrict__ h2b,
    float* __restrict__ dout)
{
  cooperative_groups::grid_group grid = cooperative_groups::this_grid();
  const int tid  = threadIdx.x;
  const int lane = tid & 63;
  const int wv   = __builtin_amdgcn_readfirstlane((tid >> 6) & 3);
  const int half = __builtin_amdgcn_readfirstlane(tid >> 8);
  const int nt   = blockIdx.x & 31;
  const int bg   = blockIdx.x >> 5;
  const int b0   = bg * 64;
  const int bglob= b0 + lane;
  const int n0w  = nt*16 + wv*4;
  // provably-divergent zero: forces weight loads onto the VMEM pipe
  const int vz   = __builtin_amdgcn_mbcnt_lo(0u, 0u);

  __shared__ float A_lds[2][2][8][64][4];  // [half][buf][kq][b][k%4] = 32 KB
  __shared__ float red[4][16][64];         // K-split partials          = 16 KB
  __shared__ float out_sh[NC][64];         // sampled feedback [c][b]
  __shared__ float h2_sh[32][64];          // logits staging [n][b]

  int t = 0;
  const float *h1prev, *h2prevB, *h2samp;
  float *h1new, *h2new;

  // ---- stage my half's 32-k chunk into A_lds[half][buf] (4 waves per half) ----
  auto stageA = [&](int buf, int mode, const float* H, int chunk){
    int kc = chunk * 32;
    #pragma unroll
    for (int it = 0; it < 2; it++){
      int kq = wv + it*4;
      float v[4];
      #pragma unroll
      for (int j = 0; j < 4; j++){
        int kg = kc + kq*4 + j;
        float x;
        if (mode == 0){
          if (kg < 9)        x = out_sh[kg][lane];
          else if (kg < 265) x = xinT[(size_t)(t*H2D + (kg-9))*512 + bglob];
          else if (kg < 274) x = skelT[(size_t)(t*NC + (kg-265))*512 + bglob];
          else               x = 0.f;
        } else {
          x = H[(size_t)kg*512 + bglob];
        }
        v[j] = x;
      }
      *(float4*)&A_lds[half][buf][kq][lane][0] = make_float4(v[0],v[1],v[2],v[3]);
    }
  };

  // ---- compute one 32-k chunk: W via VMEM uniform loads, 2-deep pipeline ----
  auto gemm_chunk = [&](int buf, const float* Wt, int kabs,
                        float* aR, float* aZ, float* aN){
    float wb[2][48];
    auto loadW = [&](int slot, int kb){
      #pragma unroll
      for (int j = 0; j < 4; j++){
        const float* wk = Wt + (size_t)(kb + j)*1536 + n0w + vz;
        *(float4*)&wb[slot][j*12 + 0] = *(const float4*)(wk);
        *(float4*)&wb[slot][j*12 + 4] = *(const float4*)(wk + 512);
        *(float4*)&wb[slot][j*12 + 8] = *(const float4*)(wk + 1024);
      }
    };
    loadW(0, kabs);
    #pragma unroll
    for (int g = 0; g < 8; g++){
      if (g + 1 < 8) loadW((g+1)&1, kabs + (g+1)*4);
      float4 a4 = *(const float4*)&A_lds[half][buf][g][lane][0];
      const float av[4] = {a4.x, a4.y, a4.z, a4.w};
      const int s = g & 1;
      #pragma unroll
      for (int j = 0; j < 4; j++){
        float a = av[j];
        #pragma unroll
        for (int h = 0; h < 4; h++) aR[h] += wb[s][j*12 + h]      * a;
        #pragma unroll
        for (int h = 0; h < 4; h++) aZ[h] += wb[s][j*12 + 4 + h]  * a;
        #pragma unroll
        for (int h = 0; h < 4; h++) aN[h] += wb[s][j*12 + 8 + h]  * a;
      }
    }
  };

  // ---- one GEMM phase, K split across halves; uniform barriers ----
  auto run_phase = [&](int mode, const float* H, const float* Wt,
                       int NITER, int mybase, int mynch,
                       float* aR, float* aZ, float* aN){
    if (mynch > 0) stageA(0, mode, H, mybase);
    __syncthreads();
    for (int c = 0; c < NITER; c++){
      if (c + 1 < mynch) stageA((c+1)&1, mode, H, mybase + c + 1);
      if (c < mynch)     gemm_chunk(c&1, Wt, (mybase + c)*32, aR, aZ, aN);
      __syncthreads();
    }
  };

  // ---- K-split reduce + GRU gates + h' write (half0 does epilogue) ----
  auto reduce_gates = [&](const float* hp_src, const float* bih, const float* bhh,
                          float* hdst, float* aR, float* aZ, float* aI, float* aH){
    if (half == 1){
      #pragma unroll
      for (int h = 0; h < 4; h++){
        red[wv][h][lane]      = aR[h];
        red[wv][4 + h][lane]  = aZ[h];
        red[wv][8 + h][lane]  = aI[h];
        red[wv][12 + h][lane] = aH[h];
      }
    }
    __syncthreads();
    if (half == 0){
      #pragma unroll
      for (int h = 0; h < 4; h++){
        float vR = aR[h] + red[wv][h][lane];
        float vZ = aZ[h] + red[wv][4 + h][lane];
        float vI = aI[h] + red[wv][8 + h][lane];
        float vH = aH[h] + red[wv][12 + h][lane];
        int n = n0w + h;
        float r  = 1.f/(1.f + expf(-(vR + bih[n] + bhh[n])));
        float z  = 1.f/(1.f + expf(-(vZ + bih[512+n] + bhh[512+n])));
        float nn = tanhf(vI + bih[1024+n] + r*(vH + bhh[1024+n]));
        float hp = hp_src[(size_t)n*512 + bglob];
        hdst[(size_t)n*512 + bglob] = (1.f - z)*nn + z*hp;
      }
    }
  };

  auto sample = [&](){
    if (t == 0){
      for (int idx = tid; idx < NC*64; idx += 512) out_sh[idx >> 6][idx & 63] = 0.f;
      __syncthreads();
      return;
    }
    float lacc[2] = {0.f, 0.f};
    for (int nc = 0; nc < 512; nc += 32){
      #pragma unroll
      for (int j = 0; j < 4; j++){
        int e = j*512 + tid;
        h2_sh[e >> 6][e & 63] = h2samp[(size_t)(nc + (e >> 6))*512 + b0 + (e & 63)];
      }
      __syncthreads();
      int slot = 0;
      for (int idx = tid; idx < 576; idx += 512, slot++){
        int c = idx >> 6, bl = idx & 63;
        const float* wr = nw + c*512 + nc;
        float s = lacc[slot];
        #pragma unroll 8
        for (int nn = 0; nn < 32; nn++) s += h2_sh[nn][bl]*wr[nn];
        lacc[slot] = s;
      }
      __syncthreads();
    }
    int slot = 0;
    for (int idx = tid; idx < 576; idx += 512, slot++){
      int c = idx >> 6, bl = idx & 63;
      float logit = lacc[slot] + nbias[c];
      if (nt == 0) dout[((size_t)(b0 + bl)*SLEN + (t-1))*NC + c] = logit;
      if (t <= 63){
        u32 ka, kb2; step_key(t-1, ka, kb2);
        float r = rng_uniform(ka, kb2, (u32)((b0 + bl)*NC + c));
        float sg = 1.f/(1.f + expf(-logit));
        out_sh[c][bl] = (sg - r > 0.f) ? 1.f : 0.f;
      }
    }
    __syncthreads();
  };

  for (t = 0; t <= 64; t++){
    h1prev  = (t & 1) ? h1b : h1a;
    h1new   = (t & 1) ? h1a : h1b;
    h2new   = (t & 1) ? h2b : h2a;
    h2prevB = (t == 0) ? h1new : ((t & 1) ? h2a : h2b);
    h2samp  = ((t-1) & 1) ? h2b : h2a;

    sample();
    if (t == 64) break;

    // ---- GRU1: cat-GEMM (9 chunks: 5/4 split) + h-GEMM (16: 8/8) ----
    float aR[4] = {0,0,0,0}, aZ[4] = {0,0,0,0}, aI[4] = {0,0,0,0}, aH[4] = {0,0,0,0};
    run_phase(0, nullptr, wih1T, 5, half ? 5 : 0, half ? 4 : 5, aR, aZ, aI);
    run_phase(1, h1prev,  whh1T, 8, half ? 8 : 0, 8,            aR, aZ, aH);
    reduce_gates(h1prev, bih1, bhh1, h1new, aR, aZ, aI, aH);
    grid.sync();

    // ---- GRU2 ----
    float cR[4] = {0,0,0,0}, cZ[4] = {0,0,0,0}, cI[4] = {0,0,0,0}, cH[4] = {0,0,0,0};
    run_phase(1, h1new,   wih2T, 8, half ? 8 : 0, 8, cR, cZ, cI);
    run_phase(1, h2prevB, whh2T, 8, half ? 8 : 0, 8, cR, cZ, cH);
    reduce_gates(h2prevB, bih2, bhh2, h2new, cR, cZ, cI, cH);
    grid.sync();
  }
}

// ---------------- host ----------------
extern "C" void kernel_launch(void* const* d_in, const int* in_sizes, int n_in,
                              void* d_out, int out_size, void* d_ws, size_t ws_size,
                              hipStream_t stream) {
  (void)in_sizes; (void)n_in; (void)out_size; (void)ws_size;
  const float* z       = (const float*)d_in[0];
  const float* skel    = (const float*)d_in[2];
  const float* se      = (const float*)d_in[3];
  const float* ct1_w   = (const float*)d_in[6];
  const float* ct1_b   = (const float*)d_in[7];
  const float* bn1_g   = (const float*)d_in[8];
  const float* bn1_b   = (const float*)d_in[9];
  const float* bn1_m   = (const float*)d_in[10];
  const float* bn1_v   = (const float*)d_in[11];
  const float* ct2_w   = (const float*)d_in[12];
  const float* ct2_b   = (const float*)d_in[13];
  const float* bn2_g   = (const float*)d_in[14];
  const float* bn2_b   = (const float*)d_in[15];
  const float* bn2_m   = (const float*)d_in[16];
  const float* bn2_v   = (const float*)d_in[17];
  const float* hfc_w   = (const float*)d_in[18];
  const float* hfc_b   = (const float*)d_in[19];
  const float* g1_wih  = (const float*)d_in[20];
  const float* g1_whh  = (const float*)d_in[21];
  const float* g1_bih  = (const float*)d_in[22];
  const float* g1_bhh  = (const float*)d_in[23];
  const float* g2_wih  = (const float*)d_in[24];
  const float* g2_whh  = (const float*)d_in[25];
  const float* g2_bih  = (const float*)d_in[26];
  const float* g2_bhh  = (const float*)d_in[27];
  const float* nfc_w   = (const float*)d_in[28];
  const float* nfc_b   = (const float*)d_in[29];

  float* ws = (float*)d_ws;
  float* y1   = ws;                        // [0, 9,175,040) floats
  float* xinT = ws + 9175040;              // 64*256*512 = 8,388,608
  float* wih1T = ws;                       // 288*1536   = 442,368 (aliases dead y1)
  float* whh1T = ws + 442368;              // 512*1536   = 786,432
  float* wih2T = ws + 1228800;
  float* whh2T = ws + 2015232;
  float* skelT = ws + 2801664;             // 64*9*512   = 294,912
  float* h1a   = ws + 3096576;             // 262,144 each
  float* h1b   = ws + 3358720;
  float* h2a   = ws + 3620864;
  float* h2b   = ws + 3883008;             // ends 4,145,152 < 9,175,040 ok
  float* dout  = (float*)d_out;

  k_conv1<<<dim3(L1, BATCH/8), 256, 0, stream>>>(z, ct1_w, ct1_b, bn1_g, bn1_b, bn1_m, bn1_v, y1);
  k_conv2<<<dim3(SLEN, BATCH/8), 256, 0, stream>>>(y1, ct2_w, ct2_b, bn2_g, bn2_b, bn2_m, bn2_v, xinT);
  k_prep<<<2048, 256, 0, stream>>>(g1_wih, g1_whh, g2_wih, g2_whh, skel,
                                   wih1T, whh1T, wih2T, whh2T, skelT);
  k_h0<<<BATCH, 256, 0, stream>>>(se, hfc_w, hfc_b, h1a);

  void* args[] = {
    (void*)&xinT, (void*)&skelT, (void*)&wih1T, (void*)&whh1T,
    (void*)&wih2T, (void*)&whh2T, (void*)&g1_bih, (void*)&g1_bhh,
    (void*)&g2_bih, (void*)&g2_bhh, (void*)&nfc_w, (void*)&nfc_b,
    (void*)&h1a, (void*)&h1b, (void*)&h2a, (void*)&h2b, (void*)&dout
  };
  hipLaunchCooperativeKernel((const void*)k_persist, dim3(256), dim3(512), args, 0, stream);
}

// Round 6
// 17668.790 us; speedup vs baseline: 1.5706x; 1.0431x over previous
//
#include <hip/hip_runtime.h>
#include <hip/hip_cooperative_groups.h>
#include <stdint.h>

typedef uint32_t u32;

#define DEV static __device__ __forceinline__

#define BATCH 512
#define CD    64
#define ZL    16
#define HID   512
#define H2D   256
#define NC    9
#define SLEN  64
#define L1    35
#define KCAT  288   /* 274 padded to 9*32 */

#define JAX_PARTITIONABLE 1

// ---------------- Threefry-2x32 (JAX key schedule, 20 rounds) ----------------
DEV void threefry2x32(u32 k0, u32 k1, u32 x0, u32 x1, u32 &o0, u32 &o1){
  const u32 ks2 = k0 ^ k1 ^ 0x1BD11BDAu;
#define TF_R(d) { x0 += x1; x1 = (x1 << (d)) | (x1 >> (32 - (d))); x1 ^= x0; }
  x0 += k0; x1 += k1;
  TF_R(13) TF_R(15) TF_R(26) TF_R(6)
  x0 += k1;  x1 += ks2 + 1u;
  TF_R(17) TF_R(29) TF_R(16) TF_R(24)
  x0 += ks2; x1 += k0 + 2u;
  TF_R(13) TF_R(15) TF_R(26) TF_R(6)
  x0 += k0;  x1 += k1 + 3u;
  TF_R(17) TF_R(29) TF_R(16) TF_R(24)
  x0 += k1;  x1 += ks2 + 4u;
  TF_R(13) TF_R(15) TF_R(26) TF_R(6)
  x0 += ks2; x1 += k0 + 5u;
#undef TF_R
  o0 = x0; o1 = x1;
}

DEV void step_key(int t, u32 &ka, u32 &kb){
#if JAX_PARTITIONABLE
  threefry2x32(0u, 42u, 0u, (u32)t, ka, kb);
#else
  u32 j0 = 2u*(u32)t, j1 = j0 + 1u, a0, a1;
  if (j0 < 64u){ threefry2x32(0u,42u, j0, 64u+j0, a0, a1); ka = a0; }
  else         { threefry2x32(0u,42u, j0-64u, j0, a0, a1); ka = a1; }
  if (j1 < 64u){ threefry2x32(0u,42u, j1, 64u+j1, a0, a1); kb = a0; }
  else         { threefry2x32(0u,42u, j1-64u, j1, a0, a1); kb = a1; }
#endif
}

DEV float rng_uniform(u32 ka, u32 kb, u32 f){
  u32 bits, o0, o1;
#if JAX_PARTITIONABLE
  threefry2x32(ka, kb, 0u, f, o0, o1);
  bits = o0 ^ o1;
#else
  const u32 HALF = (u32)(BATCH * NC / 2);
  if (f < HALF){ threefry2x32(ka, kb, f, f + HALF, o0, o1); bits = o0; }
  else         { threefry2x32(ka, kb, f - HALF, f, o0, o1); bits = o1; }
#endif
  u32 fb = (bits >> 9) | 0x3F800000u;
  float fv; __builtin_memcpy(&fv, &fb, 4);
  return fv - 1.0f;
}

// ---------------- ConvT1 (64->512, k=4, s=2, opad=1) + BN + LReLU ----------------
__global__ __launch_bounds__(256) void k_conv1(
    const float* __restrict__ z, const float* __restrict__ w1, const float* __restrict__ b1,
    const float* __restrict__ g1, const float* __restrict__ bt1, const float* __restrict__ m1,
    const float* __restrict__ v1, float* __restrict__ y1out)
{
  int t = blockIdx.x;
  int bg = blockIdx.y * 8;
  int tid = threadIdx.x;
  __shared__ float zsh[2][8][CD];
  int k0 = t & 1;
  int sA = (t - k0) >> 1, sB = sA - 1;
  bool vA = (sA >= 0 && sA < ZL), vB = (sB >= 0 && sB < ZL);
  for (int l = tid; l < 2*8*CD; l += 256){
    int p = l >> 9, bb = (l >> 6) & 7, i = l & 63;
    int s = p ? sB : sA; bool v = p ? vB : vA;
    zsh[p][bb][i] = v ? z[((bg + bb)*CD + i)*ZL + s] : 0.f;
  }
  __syncthreads();
  const float4* w1v = (const float4*)w1;
  for (int o = tid; o < HID; o += 256){
    float acc[8] = {0,0,0,0,0,0,0,0};
    for (int i = 0; i < CD; i++){
      float4 wv = w1v[i*HID + o];
      float wA = k0 ? wv.y : wv.x;
      float wB = k0 ? wv.w : wv.z;
      #pragma unroll
      for (int bb = 0; bb < 8; bb++)
        acc[bb] += zsh[0][bb][i]*wA + zsh[1][bb][i]*wB;
    }
    float xb = b1[o];
    float sc = g1[o] / sqrtf(v1[o] + 1e-5f);
    float mm = m1[o], be = bt1[o];
    #pragma unroll
    for (int bb = 0; bb < 8; bb++){
      float y = (acc[bb] + xb - mm)*sc + be;
      y = (y > 0.f) ? y : 0.2f*y;
      y1out[((bg + bb)*L1 + t)*HID + o] = y;
    }
  }
}

// ---------------- ConvT2 (512->256, k=4, s=2) + BN + LReLU -> xinT[t][c][b] ------
__global__ __launch_bounds__(256) void k_conv2(
    const float* __restrict__ y1, const float* __restrict__ w2, const float* __restrict__ b2,
    const float* __restrict__ g2, const float* __restrict__ bt2, const float* __restrict__ m2,
    const float* __restrict__ v2, float* __restrict__ xinT)
{
  int t = blockIdx.x;
  int bg = blockIdx.y * 8;
  int tid = threadIdx.x;
  __shared__ float ysh[2][8][HID];
  int k0 = t & 1;
  int sA = (t - k0) >> 1, sB = sA - 1;
  bool vB = (sB >= 0);
  for (int l = tid; l < 2*8*HID; l += 256){
    int p = l >> 12, bb = (l >> 9) & 7, o = l & 511;
    int s = p ? sB : sA; bool v = p ? vB : true;
    ysh[p][bb][o] = v ? y1[((bg + bb)*L1 + s)*HID + o] : 0.f;
  }
  __syncthreads();
  int c = tid;
  float acc[8] = {0,0,0,0,0,0,0,0};
  const float4* w2v = (const float4*)w2;
  for (int o4 = 0; o4 < HID; o4 += 4){
    float wA[4], wB[4];
    #pragma unroll
    for (int j = 0; j < 4; j++){
      float4 wv = w2v[(o4 + j)*H2D + c];
      wA[j] = k0 ? wv.y : wv.x;
      wB[j] = k0 ? wv.w : wv.z;
    }
    #pragma unroll
    for (int bb = 0; bb < 8; bb++){
      const float4 ya = *(const float4*)&ysh[0][bb][o4];
      const float4 yb = *(const float4*)&ysh[1][bb][o4];
      acc[bb] += ya.x*wA[0] + ya.y*wA[1] + ya.z*wA[2] + ya.w*wA[3]
               + yb.x*wB[0] + yb.y*wB[1] + yb.z*wB[2] + yb.w*wB[3];
    }
  }
  float xb = b2[c];
  float sc = g2[c] / sqrtf(v2[c] + 1e-5f);
  float mm = m2[c], be = bt2[c];
  float res[8];
  #pragma unroll
  for (int bb = 0; bb < 8; bb++){
    float y = (acc[bb] + xb - mm)*sc + be;
    res[bb] = (y > 0.f) ? y : 0.2f*y;
  }
  size_t base = (size_t)(t*H2D + c)*512 + bg;
  *(float4*)&xinT[base]     = make_float4(res[0],res[1],res[2],res[3]);
  *(float4*)&xinT[base + 4] = make_float4(res[4],res[5],res[6],res[7]);
}

// ---------------- h1_0 (transposed write h1T[n][b]) ------------------------------
__global__ __launch_bounds__(256) void k_h0(
    const float* __restrict__ se, const float* __restrict__ w, const float* __restrict__ bias,
    float* __restrict__ h1T)
{
  int b = blockIdx.x, tid = threadIdx.x;
  __shared__ float ssh[HID];
  for (int i = tid; i < HID; i += 256) ssh[i] = se[b*HID + i];
  __syncthreads();
  for (int j = tid; j < HID; j += 256){
    float acc = 0.f;
    for (int q = 0; q < HID; q++) acc += ssh[q] * w[j*HID + q];
    h1T[(size_t)j*512 + b] = acc + bias[j];
  }
}

// ---------------- prep: k-major transposed weights + skelT ------------------------
__global__ __launch_bounds__(256) void k_prep(
    const float* __restrict__ wih1, const float* __restrict__ whh1,
    const float* __restrict__ wih2, const float* __restrict__ whh2,
    const float* __restrict__ skel,
    float* __restrict__ wih1T, float* __restrict__ whh1T,
    float* __restrict__ wih2T, float* __restrict__ whh2T,
    float* __restrict__ skelT)
{
  const int NTOT = KCAT*1536 + 3*512*1536 + SLEN*NC*512;
  for (int i = blockIdx.x*256 + threadIdx.x; i < NTOT; i += gridDim.x*256){
    int r = i;
    if (r < KCAT*1536){
      int k = r / 1536, n = r - k*1536;
      wih1T[r] = (k < 274) ? wih1[(size_t)n*274 + k] : 0.f;
      continue;
    }
    r -= KCAT*1536;
    if (r < 512*1536){
      int k = r / 1536, n = r - k*1536;
      whh1T[r] = whh1[(size_t)n*512 + k];
      continue;
    }
    r -= 512*1536;
    if (r < 512*1536){
      int k = r / 1536, n = r - k*1536;
      wih2T[r] = wih2[(size_t)n*512 + k];
      continue;
    }
    r -= 512*1536;
    if (r < 512*1536){
      int k = r / 1536, n = r - k*1536;
      whh2T[r] = whh2[(size_t)n*512 + k];
      continue;
    }
    r -= 512*1536;
    {
      int b = r & 511, q = r >> 9;
      int c = q % NC, tt = q / NC;
      skelT[r] = skel[((size_t)b*SLEN + tt)*NC + c];
    }
  }
}

// ---------------- persistent recurrence kernel ------------------------------------
// grid 256 x 512thr (8 waves). XCD-swizzled: nt = (blk&7)*4 + ((blk>>3)&3) so each
// XCD's 32 blocks share 4 n-tiles -> W slice 1.4 MB, resident in that XCD's L2.
// wave = 64 lanes = 64 batch rows, 4 hcols x 3 gates. half = K-split (waves 0-3/4-7).
// Weights: uniform-address VMEM dwordx4, depth-3 register pipeline (24 outstanding).
__global__ __launch_bounds__(512, 2) void k_persist(
    const float* __restrict__ xinT, const float* __restrict__ skelT,
    const float* __restrict__ wih1T, const float* __restrict__ whh1T,
    const float* __restrict__ wih2T, const float* __restrict__ whh2T,
    const float* __restrict__ bih1,  const float* __restrict__ bhh1,
    const float* __restrict__ bih2,  const float* __restrict__ bhh2,
    const float* __restrict__ nw,    const float* __restrict__ nbias,
    float* __restrict__ h1a, float* __restrict__ h1b,
    float* __restrict__ h2a, float* __restrict__ h2b,
    float* __restrict__ dout)
{
  cooperative_groups::grid_group grid = cooperative_groups::this_grid();
  const int tid  = threadIdx.x;
  const int lane = tid & 63;
  const int wv   = __builtin_amdgcn_readfirstlane((tid >> 6) & 3);
  const int half = __builtin_amdgcn_readfirstlane(tid >> 8);
  // XCD-aware swizzle: blocks dispatch round-robin over 8 XCDs (blk % 8 = XCD).
  const int nt   = (blockIdx.x & 7)*4 + ((blockIdx.x >> 3) & 3);
  const int bg   = blockIdx.x >> 5;
  const int b0   = bg * 64;
  const int bglob= b0 + lane;
  const int n0w  = nt*16 + wv*4;
  // provably-divergent zero: forces weight loads onto the VMEM pipe
  const int vz   = __builtin_amdgcn_mbcnt_lo(0u, 0u);

  __shared__ float A_lds[2][2][8][64][4];  // [half][buf][kq][b][k%4] = 32 KB
  __shared__ float red[4][16][64];         // K-split partials          = 16 KB
  __shared__ float out_sh[NC][64];         // sampled feedback [c][b]
  __shared__ float h2_sh[32][64];          // logits staging [n][b]

  int t = 0;
  const float *h1prev, *h2prevB, *h2samp;
  float *h1new, *h2new;

  // ---- stage my half's 32-k chunk into A_lds[half][buf] (4 waves per half) ----
  auto stageA = [&](int buf, int mode, const float* H, int chunk){
    int kc = chunk * 32;
    #pragma unroll
    for (int it = 0; it < 2; it++){
      int kq = wv + it*4;
      float v[4];
      #pragma unroll
      for (int j = 0; j < 4; j++){
        int kg = kc + kq*4 + j;
        float x;
        if (mode == 0){
          if (kg < 9)        x = out_sh[kg][lane];
          else if (kg < 265) x = xinT[(size_t)(t*H2D + (kg-9))*512 + bglob];
          else if (kg < 274) x = skelT[(size_t)(t*NC + (kg-265))*512 + bglob];
          else               x = 0.f;
        } else {
          x = H[(size_t)kg*512 + bglob];
        }
        v[j] = x;
      }
      *(float4*)&A_lds[half][buf][kq][lane][0] = make_float4(v[0],v[1],v[2],v[3]);
    }
  };

  // ---- compute one 32-k chunk: W via VMEM uniform loads, depth-3 pipeline ----
  auto gemm_chunk = [&](int buf, const float* Wt, int kabs,
                        float* aR, float* aZ, float* aN){
    float wb[3][48];
    auto loadW = [&](int slot, int kb){
      #pragma unroll
      for (int j = 0; j < 4; j++){
        const float* wk = Wt + (size_t)(kb + j)*1536 + n0w + vz;
        *(float4*)&wb[slot][j*12 + 0] = *(const float4*)(wk);
        *(float4*)&wb[slot][j*12 + 4] = *(const float4*)(wk + 512);
        *(float4*)&wb[slot][j*12 + 8] = *(const float4*)(wk + 1024);
      }
    };
    loadW(0, kabs);
    loadW(1, kabs + 4);
    #pragma unroll
    for (int g = 0; g < 8; g++){
      if (g + 2 < 8) loadW((g+2)%3, kabs + (g+2)*4);
      float4 a4 = *(const float4*)&A_lds[half][buf][g][lane][0];
      const float av[4] = {a4.x, a4.y, a4.z, a4.w};
      const int s = g % 3;
      #pragma unroll
      for (int j = 0; j < 4; j++){
        float a = av[j];
        #pragma unroll
        for (int h = 0; h < 4; h++) aR[h] += wb[s][j*12 + h]      * a;
        #pragma unroll
        for (int h = 0; h < 4; h++) aZ[h] += wb[s][j*12 + 4 + h]  * a;
        #pragma unroll
        for (int h = 0; h < 4; h++) aN[h] += wb[s][j*12 + 8 + h]  * a;
      }
    }
  };

  // ---- one GEMM phase, K split across halves; uniform barriers ----
  auto run_phase = [&](int mode, const float* H, const float* Wt,
                       int NITER, int mybase, int mynch,
                       float* aR, float* aZ, float* aN){
    if (mynch > 0) stageA(0, mode, H, mybase);
    __syncthreads();
    for (int c = 0; c < NITER; c++){
      if (c + 1 < mynch) stageA((c+1)&1, mode, H, mybase + c + 1);
      if (c < mynch)     gemm_chunk(c&1, Wt, (mybase + c)*32, aR, aZ, aN);
      __syncthreads();
    }
  };

  // ---- K-split reduce + GRU gates + h' write (half0 does epilogue) ----
  auto reduce_gates = [&](const float* hp_src, const float* bih, const float* bhh,
                          float* hdst, float* aR, float* aZ, float* aI, float* aH){
    if (half == 1){
      #pragma unroll
      for (int h = 0; h < 4; h++){
        red[wv][h][lane]      = aR[h];
        red[wv][4 + h][lane]  = aZ[h];
        red[wv][8 + h][lane]  = aI[h];
        red[wv][12 + h][lane] = aH[h];
      }
    }
    __syncthreads();
    if (half == 0){
      #pragma unroll
      for (int h = 0; h < 4; h++){
        float vR = aR[h] + red[wv][h][lane];
        float vZ = aZ[h] + red[wv][4 + h][lane];
        float vI = aI[h] + red[wv][8 + h][lane];
        float vH = aH[h] + red[wv][12 + h][lane];
        int n = n0w + h;
        float r  = 1.f/(1.f + expf(-(vR + bih[n] + bhh[n])));
        float z  = 1.f/(1.f + expf(-(vZ + bih[512+n] + bhh[512+n])));
        float nn = tanhf(vI + bih[1024+n] + r*(vH + bhh[1024+n]));
        float hp = hp_src[(size_t)n*512 + bglob];
        hdst[(size_t)n*512 + bglob] = (1.f - z)*nn + z*hp;
      }
    }
  };

  auto sample = [&](){
    if (t == 0){
      for (int idx = tid; idx < NC*64; idx += 512) out_sh[idx >> 6][idx & 63] = 0.f;
      __syncthreads();
      return;
    }
    float lacc[2] = {0.f, 0.f};
    for (int nc = 0; nc < 512; nc += 32){
      #pragma unroll
      for (int j = 0; j < 4; j++){
        int e = j*512 + tid;
        h2_sh[e >> 6][e & 63] = h2samp[(size_t)(nc + (e >> 6))*512 + b0 + (e & 63)];
      }
      __syncthreads();
      int slot = 0;
      for (int idx = tid; idx < 576; idx += 512, slot++){
        int c = idx >> 6, bl = idx & 63;
        const float* wr = nw + c*512 + nc;
        float s = lacc[slot];
        #pragma unroll 8
        for (int nn = 0; nn < 32; nn++) s += h2_sh[nn][bl]*wr[nn];
        lacc[slot] = s;
      }
      __syncthreads();
    }
    int slot = 0;
    for (int idx = tid; idx < 576; idx += 512, slot++){
      int c = idx >> 6, bl = idx & 63;
      float logit = lacc[slot] + nbias[c];
      if (nt == 0) dout[((size_t)(b0 + bl)*SLEN + (t-1))*NC + c] = logit;
      if (t <= 63){
        u32 ka, kb2; step_key(t-1, ka, kb2);
        float r = rng_uniform(ka, kb2, (u32)((b0 + bl)*NC + c));
        float sg = 1.f/(1.f + expf(-logit));
        out_sh[c][bl] = (sg - r > 0.f) ? 1.f : 0.f;
      }
    }
    __syncthreads();
  };

  for (t = 0; t <= 64; t++){
    h1prev  = (t & 1) ? h1b : h1a;
    h1new   = (t & 1) ? h1a : h1b;
    h2new   = (t & 1) ? h2b : h2a;
    h2prevB = (t == 0) ? h1new : ((t & 1) ? h2a : h2b);
    h2samp  = ((t-1) & 1) ? h2b : h2a;

    sample();
    if (t == 64) break;

    // ---- GRU1: cat-GEMM (9 chunks: 5/4 split) + h-GEMM (16: 8/8) ----
    float aR[4] = {0,0,0,0}, aZ[4] = {0,0,0,0}, aI[4] = {0,0,0,0}, aH[4] = {0,0,0,0};
    run_phase(0, nullptr, wih1T, 5, half ? 5 : 0, half ? 4 : 5, aR, aZ, aI);
    run_phase(1, h1prev,  whh1T, 8, half ? 8 : 0, 8,            aR, aZ, aH);
    reduce_gates(h1prev, bih1, bhh1, h1new, aR, aZ, aI, aH);
    grid.sync();

    // ---- GRU2 ----
    float cR[4] = {0,0,0,0}, cZ[4] = {0,0,0,0}, cI[4] = {0,0,0,0}, cH[4] = {0,0,0,0};
    run_phase(1, h1new,   wih2T, 8, half ? 8 : 0, 8, cR, cZ, cI);
    run_phase(1, h2prevB, whh2T, 8, half ? 8 : 0, 8, cR, cZ, cH);
    reduce_gates(h2prevB, bih2, bhh2, h2new, cR, cZ, cI, cH);
    grid.sync();
  }
}

// ---------------- host ----------------
extern "C" void kernel_launch(void* const* d_in, const int* in_sizes, int n_in,
                              void* d_out, int out_size, void* d_ws, size_t ws_size,
                              hipStream_t stream) {
  (void)in_sizes; (void)n_in; (void)out_size; (void)ws_size;
  const float* z       = (const float*)d_in[0];
  const float* skel    = (const float*)d_in[2];
  const float* se      = (const float*)d_in[3];
  const float* ct1_w   = (const float*)d_in[6];
  const float* ct1_b   = (const float*)d_in[7];
  const float* bn1_g   = (const float*)d_in[8];
  const float* bn1_b   = (const float*)d_in[9];
  const float* bn1_m   = (const float*)d_in[10];
  const float* bn1_v   = (const float*)d_in[11];
  const float* ct2_w   = (const float*)d_in[12];
  const float* ct2_b   = (const float*)d_in[13];
  const float* bn2_g   = (const float*)d_in[14];
  const float* bn2_b   = (const float*)d_in[15];
  const float* bn2_m   = (const float*)d_in[16];
  const float* bn2_v   = (const float*)d_in[17];
  const float* hfc_w   = (const float*)d_in[18];
  const float* hfc_b   = (const float*)d_in[19];
  const float* g1_wih  = (const float*)d_in[20];
  const float* g1_whh  = (const float*)d_in[21];
  const float* g1_bih  = (const float*)d_in[22];
  const float* g1_bhh  = (const float*)d_in[23];
  const float* g2_wih  = (const float*)d_in[24];
  const float* g2_whh  = (const float*)d_in[25];
  const float* g2_bih  = (const float*)d_in[26];
  const float* g2_bhh  = (const float*)d_in[27];
  const float* nfc_w   = (const float*)d_in[28];
  const float* nfc_b   = (const float*)d_in[29];

  float* ws = (float*)d_ws;
  float* y1   = ws;                        // [0, 9,175,040) floats
  float* xinT = ws + 9175040;              // 64*256*512 = 8,388,608
  float* wih1T = ws;                       // 288*1536   = 442,368 (aliases dead y1)
  float* whh1T = ws + 442368;              // 512*1536   = 786,432
  float* wih2T = ws + 1228800;
  float* whh2T = ws + 2015232;
  float* skelT = ws + 2801664;             // 64*9*512   = 294,912
  float* h1a   = ws + 3096576;             // 262,144 each
  float* h1b   = ws + 3358720;
  float* h2a   = ws + 3620864;
  float* h2b   = ws + 3883008;             // ends 4,145,152 < 9,175,040 ok
  float* dout  = (float*)d_out;

  k_conv1<<<dim3(L1, BATCH/8), 256, 0, stream>>>(z, ct1_w, ct1_b, bn1_g, bn1_b, bn1_m, bn1_v, y1);
  k_conv2<<<dim3(SLEN, BATCH/8), 256, 0, stream>>>(y1, ct2_w, ct2_b, bn2_g, bn2_b, bn2_m, bn2_v, xinT);
  k_prep<<<2048, 256, 0, stream>>>(g1_wih, g1_whh, g2_wih, g2_whh, skel,
                                   wih1T, whh1T, wih2T, whh2T, skelT);
  k_h0<<<BATCH, 256, 0, stream>>>(se, hfc_w, hfc_b, h1a);

  void* args[] = {
    (void*)&xinT, (void*)&skelT, (void*)&wih1T, (void*)&whh1T,
    (void*)&wih2T, (void*)&whh2T, (void*)&g1_bih, (void*)&g1_bhh,
    (void*)&g2_bih, (void*)&g2_bhh, (void*)&nfc_w, (void*)&nfc_b,
    (void*)&h1a, (void*)&h1b, (void*)&h2a, (void*)&h2b, (void*)&dout
  };
  hipLaunchCooperativeKernel((const void*)k_persist, dim3(256), dim3(512), args, 0, stream);
}

// Round 7
// 16121.455 us; speedup vs baseline: 1.7214x; 1.0960x over previous
//
#include <hip/hip_runtime.h>
#include <stdint.h>

typedef uint32_t u32;

#define DEV static __device__ __forceinline__

#define BATCH 512
#define CD    64
#define ZL    16
#define HID   512
#define H2D   256
#define NC    9
#define SLEN  64
#define L1    35
#define KCAT  288   /* 274 padded to 9*32 */

#define JAX_PARTITIONABLE 1

// ---- agent-scope (cross-XCD coherent, L2-bypass sc1) element access ----
DEV float g_load(const float* p){
  return __hip_atomic_load(p, __ATOMIC_RELAXED, __HIP_MEMORY_SCOPE_AGENT);
}
DEV void g_store(float* p, float v){
  __hip_atomic_store(p, v, __ATOMIC_RELAXED, __HIP_MEMORY_SCOPE_AGENT);
}

// ---------------- Threefry-2x32 (JAX key schedule, 20 rounds) ----------------
DEV void threefry2x32(u32 k0, u32 k1, u32 x0, u32 x1, u32 &o0, u32 &o1){
  const u32 ks2 = k0 ^ k1 ^ 0x1BD11BDAu;
#define TF_R(d) { x0 += x1; x1 = (x1 << (d)) | (x1 >> (32 - (d))); x1 ^= x0; }
  x0 += k0; x1 += k1;
  TF_R(13) TF_R(15) TF_R(26) TF_R(6)
  x0 += k1;  x1 += ks2 + 1u;
  TF_R(17) TF_R(29) TF_R(16) TF_R(24)
  x0 += ks2; x1 += k0 + 2u;
  TF_R(13) TF_R(15) TF_R(26) TF_R(6)
  x0 += k0;  x1 += k1 + 3u;
  TF_R(17) TF_R(29) TF_R(16) TF_R(24)
  x0 += k1;  x1 += ks2 + 4u;
  TF_R(13) TF_R(15) TF_R(26) TF_R(6)
  x0 += ks2; x1 += k0 + 5u;
#undef TF_R
  o0 = x0; o1 = x1;
}

DEV void step_key(int t, u32 &ka, u32 &kb){
#if JAX_PARTITIONABLE
  threefry2x32(0u, 42u, 0u, (u32)t, ka, kb);
#else
  u32 j0 = 2u*(u32)t, j1 = j0 + 1u, a0, a1;
  if (j0 < 64u){ threefry2x32(0u,42u, j0, 64u+j0, a0, a1); ka = a0; }
  else         { threefry2x32(0u,42u, j0-64u, j0, a0, a1); ka = a1; }
  if (j1 < 64u){ threefry2x32(0u,42u, j1, 64u+j1, a0, a1); kb = a0; }
  else         { threefry2x32(0u,42u, j1-64u, j1, a0, a1); kb = a1; }
#endif
}

DEV float rng_uniform(u32 ka, u32 kb, u32 f){
  u32 bits, o0, o1;
#if JAX_PARTITIONABLE
  threefry2x32(ka, kb, 0u, f, o0, o1);
  bits = o0 ^ o1;
#else
  const u32 HALF = (u32)(BATCH * NC / 2);
  if (f < HALF){ threefry2x32(ka, kb, f, f + HALF, o0, o1); bits = o0; }
  else         { threefry2x32(ka, kb, f - HALF, f, o0, o1); bits = o1; }
#endif
  u32 fb = (bits >> 9) | 0x3F800000u;
  float fv; __builtin_memcpy(&fv, &fb, 4);
  return fv - 1.0f;
}

// ---------------- ConvT1 (64->512, k=4, s=2, opad=1) + BN + LReLU ----------------
__global__ __launch_bounds__(256) void k_conv1(
    const float* __restrict__ z, const float* __restrict__ w1, const float* __restrict__ b1,
    const float* __restrict__ g1, const float* __restrict__ bt1, const float* __restrict__ m1,
    const float* __restrict__ v1, float* __restrict__ y1out)
{
  int t = blockIdx.x;
  int bg = blockIdx.y * 8;
  int tid = threadIdx.x;
  __shared__ float zsh[2][8][CD];
  int k0 = t & 1;
  int sA = (t - k0) >> 1, sB = sA - 1;
  bool vA = (sA >= 0 && sA < ZL), vB = (sB >= 0 && sB < ZL);
  for (int l = tid; l < 2*8*CD; l += 256){
    int p = l >> 9, bb = (l >> 6) & 7, i = l & 63;
    int s = p ? sB : sA; bool v = p ? vB : vA;
    zsh[p][bb][i] = v ? z[((bg + bb)*CD + i)*ZL + s] : 0.f;
  }
  __syncthreads();
  const float4* w1v = (const float4*)w1;
  for (int o = tid; o < HID; o += 256){
    float acc[8] = {0,0,0,0,0,0,0,0};
    for (int i = 0; i < CD; i++){
      float4 wv = w1v[i*HID + o];
      float wA = k0 ? wv.y : wv.x;
      float wB = k0 ? wv.w : wv.z;
      #pragma unroll
      for (int bb = 0; bb < 8; bb++)
        acc[bb] += zsh[0][bb][i]*wA + zsh[1][bb][i]*wB;
    }
    float xb = b1[o];
    float sc = g1[o] / sqrtf(v1[o] + 1e-5f);
    float mm = m1[o], be = bt1[o];
    #pragma unroll
    for (int bb = 0; bb < 8; bb++){
      float y = (acc[bb] + xb - mm)*sc + be;
      y = (y > 0.f) ? y : 0.2f*y;
      y1out[((bg + bb)*L1 + t)*HID + o] = y;
    }
  }
}

// ---------------- ConvT2 (512->256, k=4, s=2) + BN + LReLU -> xinT[t][c][b] ------
__global__ __launch_bounds__(256) void k_conv2(
    const float* __restrict__ y1, const float* __restrict__ w2, const float* __restrict__ b2,
    const float* __restrict__ g2, const float* __restrict__ bt2, const float* __restrict__ m2,
    const float* __restrict__ v2, float* __restrict__ xinT)
{
  int t = blockIdx.x;
  int bg = blockIdx.y * 8;
  int tid = threadIdx.x;
  __shared__ float ysh[2][8][HID];
  int k0 = t & 1;
  int sA = (t - k0) >> 1, sB = sA - 1;
  bool vB = (sB >= 0);
  for (int l = tid; l < 2*8*HID; l += 256){
    int p = l >> 12, bb = (l >> 9) & 7, o = l & 511;
    int s = p ? sB : sA; bool v = p ? vB : true;
    ysh[p][bb][o] = v ? y1[((bg + bb)*L1 + s)*HID + o] : 0.f;
  }
  __syncthreads();
  int c = tid;
  float acc[8] = {0,0,0,0,0,0,0,0};
  const float4* w2v = (const float4*)w2;
  for (int o4 = 0; o4 < HID; o4 += 4){
    float wA[4], wB[4];
    #pragma unroll
    for (int j = 0; j < 4; j++){
      float4 wv = w2v[(o4 + j)*H2D + c];
      wA[j] = k0 ? wv.y : wv.x;
      wB[j] = k0 ? wv.w : wv.z;
    }
    #pragma unroll
    for (int bb = 0; bb < 8; bb++){
      const float4 ya = *(const float4*)&ysh[0][bb][o4];
      const float4 yb = *(const float4*)&ysh[1][bb][o4];
      acc[bb] += ya.x*wA[0] + ya.y*wA[1] + ya.z*wA[2] + ya.w*wA[3]
               + yb.x*wB[0] + yb.y*wB[1] + yb.z*wB[2] + yb.w*wB[3];
    }
  }
  float xb = b2[c];
  float sc = g2[c] / sqrtf(v2[c] + 1e-5f);
  float mm = m2[c], be = bt2[c];
  float res[8];
  #pragma unroll
  for (int bb = 0; bb < 8; bb++){
    float y = (acc[bb] + xb - mm)*sc + be;
    res[bb] = (y > 0.f) ? y : 0.2f*y;
  }
  size_t base = (size_t)(t*H2D + c)*512 + bg;
  *(float4*)&xinT[base]     = make_float4(res[0],res[1],res[2],res[3]);
  *(float4*)&xinT[base + 4] = make_float4(res[4],res[5],res[6],res[7]);
}

// ---------------- h1_0 (transposed write h1T[n][b]) ------------------------------
__global__ __launch_bounds__(256) void k_h0(
    const float* __restrict__ se, const float* __restrict__ w, const float* __restrict__ bias,
    float* __restrict__ h1T)
{
  int b = blockIdx.x, tid = threadIdx.x;
  __shared__ float ssh[HID];
  for (int i = tid; i < HID; i += 256) ssh[i] = se[b*HID + i];
  __syncthreads();
  for (int j = tid; j < HID; j += 256){
    float acc = 0.f;
    for (int q = 0; q < HID; q++) acc += ssh[q] * w[j*HID + q];
    h1T[(size_t)j*512 + b] = acc + bias[j];
  }
}

// ---------------- prep: k-major transposed weights + skelT + barrier zero --------
__global__ __launch_bounds__(256) void k_prep(
    const float* __restrict__ wih1, const float* __restrict__ whh1,
    const float* __restrict__ wih2, const float* __restrict__ whh2,
    const float* __restrict__ skel,
    float* __restrict__ wih1T, float* __restrict__ whh1T,
    float* __restrict__ wih2T, float* __restrict__ whh2T,
    float* __restrict__ skelT, u32* __restrict__ bar)
{
  if (blockIdx.x == 0 && threadIdx.x < 64) bar[threadIdx.x] = 0u;
  const int NTOT = KCAT*1536 + 3*512*1536 + SLEN*NC*512;
  for (int i = blockIdx.x*256 + threadIdx.x; i < NTOT; i += gridDim.x*256){
    int r = i;
    if (r < KCAT*1536){
      int k = r / 1536, n = r - k*1536;
      wih1T[r] = (k < 274) ? wih1[(size_t)n*274 + k] : 0.f;
      continue;
    }
    r -= KCAT*1536;
    if (r < 512*1536){
      int k = r / 1536, n = r - k*1536;
      whh1T[r] = whh1[(size_t)n*512 + k];
      continue;
    }
    r -= 512*1536;
    if (r < 512*1536){
      int k = r / 1536, n = r - k*1536;
      wih2T[r] = wih2[(size_t)n*512 + k];
      continue;
    }
    r -= 512*1536;
    if (r < 512*1536){
      int k = r / 1536, n = r - k*1536;
      whh2T[r] = whh2[(size_t)n*512 + k];
      continue;
    }
    r -= 512*1536;
    {
      int b = r & 511, q = r >> 9;
      int c = q % NC, tt = q / NC;
      skelT[r] = skel[((size_t)b*SLEN + tt)*NC + c];
    }
  }
}

// ---------------- persistent recurrence kernel ------------------------------------
// grid 256 x 512thr (8 waves). XCD-swizzled: nt = (blk&7)*4 + ((blk>>3)&3) so each
// XCD's blocks share 4 n-tiles -> 1.4 MB W slice stays resident in that XCD's L2
// (no grid.sync L2-invalidate anymore). h-state moves via agent-scope sc1 accesses.
// Custom monotonic barrier: release fetch_add + relaxed spin, no cache invalidate.
__global__ __launch_bounds__(512, 2) void k_persist(
    const float* __restrict__ xinT, const float* __restrict__ skelT,
    const float* __restrict__ wih1T, const float* __restrict__ whh1T,
    const float* __restrict__ wih2T, const float* __restrict__ whh2T,
    const float* __restrict__ bih1,  const float* __restrict__ bhh1,
    const float* __restrict__ bih2,  const float* __restrict__ bhh2,
    const float* __restrict__ nw,    const float* __restrict__ nbias,
    float* __restrict__ h1a, float* __restrict__ h1b,
    float* __restrict__ h2a, float* __restrict__ h2b,
    float* __restrict__ dout, u32* __restrict__ bar)
{
  const int tid  = threadIdx.x;
  const int lane = tid & 63;
  const int wv   = __builtin_amdgcn_readfirstlane((tid >> 6) & 3);
  const int half = __builtin_amdgcn_readfirstlane(tid >> 8);
  const int nt   = (blockIdx.x & 7)*4 + ((blockIdx.x >> 3) & 3);
  const int bg   = blockIdx.x >> 5;
  const int b0   = bg * 64;
  const int bglob= b0 + lane;
  const int n0w  = nt*16 + wv*4;
  const int vz   = __builtin_amdgcn_mbcnt_lo(0u, 0u);  // divergent zero -> VMEM pipe

  __shared__ float A_lds[2][2][8][64][4];  // [half][buf][kq][b][k%4] = 32 KB
  __shared__ float red[4][16][64];         // K-split partials          = 16 KB
  __shared__ float out_sh[NC][64];         // sampled feedback [c][b]
  __shared__ float h2_sh[32][64];          // logits staging [n][b]

  int t = 0;
  int bar_idx = 0;
  const float *h1prev, *h2prevB, *h2samp;
  float *h1new, *h2new;

  // ---- global barrier: no L2 invalidate (W stays cached). __syncthreads drains
  // each wave's sc1 stores (vmcnt0) to the L3 coherence point before signaling. ----
  auto gbar = [&](){
    __syncthreads();
    if (tid == 0){
      __hip_atomic_fetch_add(bar, 1u, __ATOMIC_RELEASE, __HIP_MEMORY_SCOPE_AGENT);
      u32 target = 256u*(u32)(bar_idx + 1);
      while (__hip_atomic_load(bar, __ATOMIC_RELAXED, __HIP_MEMORY_SCOPE_AGENT) < target)
        __builtin_amdgcn_s_sleep(2);
    }
    bar_idx++;
    __syncthreads();
  };

  // ---- stage my half's 32-k chunk into A_lds[half][buf] ----
  auto stageA = [&](int buf, int mode, const float* H, int chunk){
    int kc = chunk * 32;
    #pragma unroll
    for (int it = 0; it < 2; it++){
      int kq = wv + it*4;
      float v[4];
      #pragma unroll
      for (int j = 0; j < 4; j++){
        int kg = kc + kq*4 + j;
        float x;
        if (mode == 0){
          if (kg < 9)        x = out_sh[kg][lane];
          else if (kg < 265) x = xinT[(size_t)(t*H2D + (kg-9))*512 + bglob];
          else if (kg < 274) x = skelT[(size_t)(t*NC + (kg-265))*512 + bglob];
          else               x = 0.f;
        } else {
          x = g_load(&H[(size_t)kg*512 + bglob]);
        }
        v[j] = x;
      }
      *(float4*)&A_lds[half][buf][kq][lane][0] = make_float4(v[0],v[1],v[2],v[3]);
    }
  };

  // ---- compute one 32-k chunk: W via VMEM uniform loads, depth-3 pipeline ----
  auto gemm_chunk = [&](int buf, const float* Wt, int kabs,
                        float* aR, float* aZ, float* aN){
    float wb[3][48];
    auto loadW = [&](int slot, int kb){
      #pragma unroll
      for (int j = 0; j < 4; j++){
        const float* wk = Wt + (size_t)(kb + j)*1536 + n0w + vz;
        *(float4*)&wb[slot][j*12 + 0] = *(const float4*)(wk);
        *(float4*)&wb[slot][j*12 + 4] = *(const float4*)(wk + 512);
        *(float4*)&wb[slot][j*12 + 8] = *(const float4*)(wk + 1024);
      }
    };
    loadW(0, kabs);
    loadW(1, kabs + 4);
    #pragma unroll
    for (int g = 0; g < 8; g++){
      if (g + 2 < 8) loadW((g+2)%3, kabs + (g+2)*4);
      float4 a4 = *(const float4*)&A_lds[half][buf][g][lane][0];
      const float av[4] = {a4.x, a4.y, a4.z, a4.w};
      const int s = g % 3;
      #pragma unroll
      for (int j = 0; j < 4; j++){
        float a = av[j];
        #pragma unroll
        for (int h = 0; h < 4; h++) aR[h] += wb[s][j*12 + h]      * a;
        #pragma unroll
        for (int h = 0; h < 4; h++) aZ[h] += wb[s][j*12 + 4 + h]  * a;
        #pragma unroll
        for (int h = 0; h < 4; h++) aN[h] += wb[s][j*12 + 8 + h]  * a;
      }
    }
  };

  // ---- one GEMM phase, K split across halves; uniform barriers ----
  auto run_phase = [&](int mode, const float* H, const float* Wt,
                       int NITER, int mybase, int mynch,
                       float* aR, float* aZ, float* aN){
    if (mynch > 0) stageA(0, mode, H, mybase);
    __syncthreads();
    for (int c = 0; c < NITER; c++){
      if (c + 1 < mynch) stageA((c+1)&1, mode, H, mybase + c + 1);
      if (c < mynch)     gemm_chunk(c&1, Wt, (mybase + c)*32, aR, aZ, aN);
      __syncthreads();
    }
  };

  // ---- K-split reduce + GRU gates + h' write (half0 does epilogue) ----
  auto reduce_gates = [&](const float* hp_src, const float* bih, const float* bhh,
                          float* hdst, float* aR, float* aZ, float* aI, float* aH){
    if (half == 1){
      #pragma unroll
      for (int h = 0; h < 4; h++){
        red[wv][h][lane]      = aR[h];
        red[wv][4 + h][lane]  = aZ[h];
        red[wv][8 + h][lane]  = aI[h];
        red[wv][12 + h][lane] = aH[h];
      }
    }
    __syncthreads();
    if (half == 0){
      #pragma unroll
      for (int h = 0; h < 4; h++){
        float vR = aR[h] + red[wv][h][lane];
        float vZ = aZ[h] + red[wv][4 + h][lane];
        float vI = aI[h] + red[wv][8 + h][lane];
        float vH = aH[h] + red[wv][12 + h][lane];
        int n = n0w + h;
        float r  = 1.f/(1.f + expf(-(vR + bih[n] + bhh[n])));
        float z  = 1.f/(1.f + expf(-(vZ + bih[512+n] + bhh[512+n])));
        float nn = tanhf(vI + bih[1024+n] + r*(vH + bhh[1024+n]));
        float hp = g_load(&hp_src[(size_t)n*512 + bglob]);
        g_store(&hdst[(size_t)n*512 + bglob], (1.f - z)*nn + z*hp);
      }
    }
  };

  auto sample = [&](){
    if (t == 0){
      for (int idx = tid; idx < NC*64; idx += 512) out_sh[idx >> 6][idx & 63] = 0.f;
      __syncthreads();
      return;
    }
    float lacc[2] = {0.f, 0.f};
    for (int nc = 0; nc < 512; nc += 32){
      #pragma unroll
      for (int j = 0; j < 4; j++){
        int e = j*512 + tid;
        h2_sh[e >> 6][e & 63] = g_load(&h2samp[(size_t)(nc + (e >> 6))*512 + b0 + (e & 63)]);
      }
      __syncthreads();
      int slot = 0;
      for (int idx = tid; idx < 576; idx += 512, slot++){
        int c = idx >> 6, bl = idx & 63;
        const float* wr = nw + c*512 + nc;
        float s = lacc[slot];
        #pragma unroll 8
        for (int nn = 0; nn < 32; nn++) s += h2_sh[nn][bl]*wr[nn];
        lacc[slot] = s;
      }
      __syncthreads();
    }
    int slot = 0;
    for (int idx = tid; idx < 576; idx += 512, slot++){
      int c = idx >> 6, bl = idx & 63;
      float logit = lacc[slot] + nbias[c];
      if (nt == 0) dout[((size_t)(b0 + bl)*SLEN + (t-1))*NC + c] = logit;
      if (t <= 63){
        u32 ka, kb2; step_key(t-1, ka, kb2);
        float r = rng_uniform(ka, kb2, (u32)((b0 + bl)*NC + c));
        float sg = 1.f/(1.f + expf(-logit));
        out_sh[c][bl] = (sg - r > 0.f) ? 1.f : 0.f;
      }
    }
    __syncthreads();
  };

  for (t = 0; t <= 64; t++){
    h1prev  = (t & 1) ? h1b : h1a;
    h1new   = (t & 1) ? h1a : h1b;
    h2new   = (t & 1) ? h2b : h2a;
    h2prevB = (t == 0) ? h1new : ((t & 1) ? h2a : h2b);
    h2samp  = ((t-1) & 1) ? h2b : h2a;

    sample();
    if (t == 64) break;

    // ---- GRU1 ----
    float aR[4] = {0,0,0,0}, aZ[4] = {0,0,0,0}, aI[4] = {0,0,0,0}, aH[4] = {0,0,0,0};
    run_phase(0, nullptr, wih1T, 5, half ? 5 : 0, half ? 4 : 5, aR, aZ, aI);
    run_phase(1, h1prev,  whh1T, 8, half ? 8 : 0, 8,            aR, aZ, aH);
    reduce_gates(h1prev, bih1, bhh1, h1new, aR, aZ, aI, aH);
    gbar();

    // ---- GRU2 ----
    float cR[4] = {0,0,0,0}, cZ[4] = {0,0,0,0}, cI[4] = {0,0,0,0}, cH[4] = {0,0,0,0};
    run_phase(1, h1new,   wih2T, 8, half ? 8 : 0, 8, cR, cZ, cI);
    run_phase(1, h2prevB, whh2T, 8, half ? 8 : 0, 8, cR, cZ, cH);
    reduce_gates(h2prevB, bih2, bhh2, h2new, cR, cZ, cI, cH);
    gbar();
  }
}

// ---------------- host ----------------
extern "C" void kernel_launch(void* const* d_in, const int* in_sizes, int n_in,
                              void* d_out, int out_size, void* d_ws, size_t ws_size,
                              hipStream_t stream) {
  (void)in_sizes; (void)n_in; (void)out_size; (void)ws_size;
  const float* z       = (const float*)d_in[0];
  const float* skel    = (const float*)d_in[2];
  const float* se      = (const float*)d_in[3];
  const float* ct1_w   = (const float*)d_in[6];
  const float* ct1_b   = (const float*)d_in[7];
  const float* bn1_g   = (const float*)d_in[8];
  const float* bn1_b   = (const float*)d_in[9];
  const float* bn1_m   = (const float*)d_in[10];
  const float* bn1_v   = (const float*)d_in[11];
  const float* ct2_w   = (const float*)d_in[12];
  const float* ct2_b   = (const float*)d_in[13];
  const float* bn2_g   = (const float*)d_in[14];
  const float* bn2_b   = (const float*)d_in[15];
  const float* bn2_m   = (const float*)d_in[16];
  const float* bn2_v   = (const float*)d_in[17];
  const float* hfc_w   = (const float*)d_in[18];
  const float* hfc_b   = (const float*)d_in[19];
  const float* g1_wih  = (const float*)d_in[20];
  const float* g1_whh  = (const float*)d_in[21];
  const float* g1_bih  = (const float*)d_in[22];
  const float* g1_bhh  = (const float*)d_in[23];
  const float* g2_wih  = (const float*)d_in[24];
  const float* g2_whh  = (const float*)d_in[25];
  const float* g2_bih  = (const float*)d_in[26];
  const float* g2_bhh  = (const float*)d_in[27];
  const float* nfc_w   = (const float*)d_in[28];
  const float* nfc_b   = (const float*)d_in[29];

  float* ws = (float*)d_ws;
  float* y1   = ws;                        // [0, 9,175,040) floats
  float* xinT = ws + 9175040;              // 64*256*512 = 8,388,608
  float* wih1T = ws;                       // 288*1536   = 442,368 (aliases dead y1)
  float* whh1T = ws + 442368;              // 512*1536   = 786,432
  float* wih2T = ws + 1228800;
  float* whh2T = ws + 2015232;
  float* skelT = ws + 2801664;             // 64*9*512   = 294,912
  float* h1a   = ws + 3096576;             // 262,144 each
  float* h1b   = ws + 3358720;
  float* h2a   = ws + 3620864;
  float* h2b   = ws + 3883008;             // ends 4,145,152
  u32*   bar   = (u32*)(ws + 4145152);     // 64 u32 barrier area < 9,175,040 ok
  float* dout  = (float*)d_out;

  k_conv1<<<dim3(L1, BATCH/8), 256, 0, stream>>>(z, ct1_w, ct1_b, bn1_g, bn1_b, bn1_m, bn1_v, y1);
  k_conv2<<<dim3(SLEN, BATCH/8), 256, 0, stream>>>(y1, ct2_w, ct2_b, bn2_g, bn2_b, bn2_m, bn2_v, xinT);
  k_prep<<<2048, 256, 0, stream>>>(g1_wih, g1_whh, g2_wih, g2_whh, skel,
                                   wih1T, whh1T, wih2T, whh2T, skelT, bar);
  k_h0<<<BATCH, 256, 0, stream>>>(se, hfc_w, hfc_b, h1a);

  void* args[] = {
    (void*)&xinT, (void*)&skelT, (void*)&wih1T, (void*)&whh1T,
    (void*)&wih2T, (void*)&whh2T, (void*)&g1_bih, (void*)&g1_bhh,
    (void*)&g2_bih, (void*)&g2_bhh, (void*)&nfc_w, (void*)&nfc_b,
    (void*)&h1a, (void*)&h1b, (void*)&h2a, (void*)&h2b, (void*)&dout, (void*)&bar
  };
  hipLaunchCooperativeKernel((const void*)k_persist, dim3(256), dim3(512), args, 0, stream);
}

// Round 9
// 9368.304 us; speedup vs baseline: 2.9622x; 1.7209x over previous
//
#include <hip/hip_runtime.h>
#include <stdint.h>

typedef uint32_t u32; typedef uint16_t u16;
typedef __attribute__((ext_vector_type(8))) short short8;
typedef __attribute__((ext_vector_type(4))) float f32x4;

#define DEV static __device__ __forceinline__
#define MFMA16 __builtin_amdgcn_mfma_f32_16x16x32_bf16

#define BATCH 512
#define CD    64
#define ZL    16
#define HID   512
#define H2D   256
#define NC    9
#define SLEN  64
#define L1    35

#define JAX_PARTITIONABLE 1

// ---- workspace layout (f32-word offsets) ----
#define P_W      2850816   /* u16 per W limb plane-set */
#define WOFF_SKH 4276224   /* skel_hi u16 [64][512][16] */
#define WOFF_HPL 4538368   /* 4 states x 3 limbs x 262144 u16 */
#define WOFF_HF  6111232   /* 4 states x 262144 f32 */
#define WOFF_LOG 7159808   /* f32 [64][512][16] */
#define WOFF_FLG 7684096   /* u32 flg[256] + go[16] */
#define WOFF_XH  9175040   /* xin limb planes: 2 x 8,388,608 u16 */

DEV float bf2f(u16 h){ u32 u = ((u32)h) << 16; float f; __builtin_memcpy(&f,&u,4); return f; }
DEV u16 f2bf(float f){ u32 u; __builtin_memcpy(&u,&f,4); return (u16)((u + 0x7FFFu + ((u>>16)&1u)) >> 16); }

DEV float ldf(const float* p){ return __hip_atomic_load(p, __ATOMIC_RELAXED, __HIP_MEMORY_SCOPE_AGENT); }
DEV void stf(float* p, float v){ __hip_atomic_store(p, v, __ATOMIC_RELAXED, __HIP_MEMORY_SCOPE_AGENT); }
DEV void sth(u16* p, u16 v){ __hip_atomic_store(p, v, __ATOMIC_RELAXED, __HIP_MEMORY_SCOPE_AGENT); }
DEV u32 ldu32(const u32* p){ return __hip_atomic_load(p, __ATOMIC_RELAXED, __HIP_MEMORY_SCOPE_AGENT); }

// ---------------- Threefry-2x32 ----------------
DEV void threefry2x32(u32 k0, u32 k1, u32 x0, u32 x1, u32 &o0, u32 &o1){
  const u32 ks2 = k0 ^ k1 ^ 0x1BD11BDAu;
#define TF_R(d) { x0 += x1; x1 = (x1 << (d)) | (x1 >> (32 - (d))); x1 ^= x0; }
  x0 += k0; x1 += k1;
  TF_R(13) TF_R(15) TF_R(26) TF_R(6)
  x0 += k1;  x1 += ks2 + 1u;
  TF_R(17) TF_R(29) TF_R(16) TF_R(24)
  x0 += ks2; x1 += k0 + 2u;
  TF_R(13) TF_R(15) TF_R(26) TF_R(6)
  x0 += k0;  x1 += k1 + 3u;
  TF_R(17) TF_R(29) TF_R(16) TF_R(24)
  x0 += k1;  x1 += ks2 + 4u;
  TF_R(13) TF_R(15) TF_R(26) TF_R(6)
  x0 += ks2; x1 += k0 + 5u;
#undef TF_R
  o0 = x0; o1 = x1;
}
DEV void step_key(int t, u32 &ka, u32 &kb){
#if JAX_PARTITIONABLE
  threefry2x32(0u, 42u, 0u, (u32)t, ka, kb);
#else
  u32 j0 = 2u*(u32)t, j1 = j0 + 1u, a0, a1;
  if (j0 < 64u){ threefry2x32(0u,42u, j0, 64u+j0, a0, a1); ka = a0; }
  else         { threefry2x32(0u,42u, j0-64u, j0, a0, a1); ka = a1; }
  if (j1 < 64u){ threefry2x32(0u,42u, j1, 64u+j1, a0, a1); kb = a0; }
  else         { threefry2x32(0u,42u, j1-64u, j1, a0, a1); kb = a1; }
#endif
}
DEV float rng_uniform(u32 ka, u32 kb, u32 f){
  u32 bits, o0, o1;
#if JAX_PARTITIONABLE
  threefry2x32(ka, kb, 0u, f, o0, o1);
  bits = o0 ^ o1;
#else
  const u32 HALF = (u32)(BATCH*NC/2);
  if (f < HALF){ threefry2x32(ka, kb, f, f+HALF, o0, o1); bits = o0; }
  else         { threefry2x32(ka, kb, f-HALF, f, o0, o1); bits = o1; }
#endif
  u32 fb = (bits >> 9) | 0x3F800000u;
  float fv; __builtin_memcpy(&fv,&fb,4);
  return fv - 1.0f;
}

// ---------------- ConvT1 ----------------
__global__ __launch_bounds__(256) void k_conv1(
    const float* __restrict__ z, const float* __restrict__ w1, const float* __restrict__ b1,
    const float* __restrict__ g1, const float* __restrict__ bt1, const float* __restrict__ m1,
    const float* __restrict__ v1, float* __restrict__ y1out)
{
  int t = blockIdx.x, bg = blockIdx.y*8, tid = threadIdx.x;
  __shared__ float zsh[2][8][CD];
  int k0 = t & 1, sA = (t-k0)>>1, sB = sA-1;
  bool vA = (sA>=0 && sA<ZL), vB = (sB>=0 && sB<ZL);
  for (int l = tid; l < 2*8*CD; l += 256){
    int p = l>>9, bb = (l>>6)&7, i = l&63;
    int s = p ? sB : sA; bool v = p ? vB : vA;
    zsh[p][bb][i] = v ? z[((bg+bb)*CD+i)*ZL + s] : 0.f;
  }
  __syncthreads();
  const float4* w1v = (const float4*)w1;
  for (int o = tid; o < HID; o += 256){
    float acc[8] = {0,0,0,0,0,0,0,0};
    for (int i = 0; i < CD; i++){
      float4 wv = w1v[i*HID + o];
      float wA = k0 ? wv.y : wv.x, wB = k0 ? wv.w : wv.z;
      #pragma unroll
      for (int bb = 0; bb < 8; bb++) acc[bb] += zsh[0][bb][i]*wA + zsh[1][bb][i]*wB;
    }
    float xb = b1[o], sc = g1[o]/sqrtf(v1[o]+1e-5f), mm = m1[o], be = bt1[o];
    #pragma unroll
    for (int bb = 0; bb < 8; bb++){
      float y = (acc[bb]+xb-mm)*sc + be;
      y = (y>0.f)? y : 0.2f*y;
      y1out[((bg+bb)*L1 + t)*HID + o] = y;
    }
  }
}

// ---------------- ConvT2 -> xin 2 limb planes [t][b][256] ----------------
__global__ __launch_bounds__(256) void k_conv2(
    const float* __restrict__ y1, const float* __restrict__ w2, const float* __restrict__ b2,
    const float* __restrict__ g2, const float* __restrict__ bt2, const float* __restrict__ m2,
    const float* __restrict__ v2, u16* __restrict__ xh, u16* __restrict__ xl)
{
  int t = blockIdx.x, bg = blockIdx.y*8, tid = threadIdx.x;
  __shared__ float ysh[2][8][HID];
  int k0 = t & 1, sA = (t-k0)>>1, sB = sA-1;
  bool vB = (sB >= 0);
  for (int l = tid; l < 2*8*HID; l += 256){
    int p = l>>12, bb = (l>>9)&7, o = l&511;
    int s = p ? sB : sA; bool v = p ? vB : true;
    ysh[p][bb][o] = v ? y1[((bg+bb)*L1 + s)*HID + o] : 0.f;
  }
  __syncthreads();
  int c = tid;
  float acc[8] = {0,0,0,0,0,0,0,0};
  const float4* w2v = (const float4*)w2;
  for (int o4 = 0; o4 < HID; o4 += 4){
    float wA[4], wB[4];
    #pragma unroll
    for (int j = 0; j < 4; j++){
      float4 wv = w2v[(o4+j)*H2D + c];
      wA[j] = k0 ? wv.y : wv.x; wB[j] = k0 ? wv.w : wv.z;
    }
    #pragma unroll
    for (int bb = 0; bb < 8; bb++){
      const float4 ya = *(const float4*)&ysh[0][bb][o4];
      const float4 yb = *(const float4*)&ysh[1][bb][o4];
      acc[bb] += ya.x*wA[0]+ya.y*wA[1]+ya.z*wA[2]+ya.w*wA[3]
               + yb.x*wB[0]+yb.y*wB[1]+yb.z*wB[2]+yb.w*wB[3];
    }
  }
  float xb = b2[c], sc = g2[c]/sqrtf(v2[c]+1e-5f), mm = m2[c], be = bt2[c];
  #pragma unroll
  for (int bb = 0; bb < 8; bb++){
    float y = (acc[bb]+xb-mm)*sc + be;
    y = (y>0.f)? y : 0.2f*y;
    u16 hi = f2bf(y); u16 lo = f2bf(y - bf2f(hi));
    size_t o = ((size_t)t*512 + bg + bb)*256 + c;
    xh[o] = hi; xl[o] = lo;
  }
}

// ---------------- prep: W 3-limb k-major planes, skel_hi, zero logacc+flags ------
__global__ __launch_bounds__(256) void k_prep(
    const float* __restrict__ wih1, const float* __restrict__ whh1,
    const float* __restrict__ wih2, const float* __restrict__ whh2,
    const float* __restrict__ skel, float* __restrict__ ws)
{
  u16* wp = (u16*)ws;
  u16* skh = (u16*)(ws + WOFF_SKH);
  float* logacc = ws + WOFF_LOG;
  u32* flg = (u32*)(ws + WOFF_FLG);
  int stride = gridDim.x*256, i0 = blockIdx.x*256 + threadIdx.x;
  for (int i = i0; i < P_W; i += stride){
    int r = i; float v;
    if (r < 491520){ int n = r/320, k = r - n*320; v = (k < 274)? wih1[(size_t)n*274 + k] : 0.f; }
    else if (r < 1277952){ int rr = r-491520;  int n = rr>>9, k = rr&511; v = whh1[((size_t)n<<9)+k]; }
    else if (r < 2064384){ int rr = r-1277952; int n = rr>>9, k = rr&511; v = wih2[((size_t)n<<9)+k]; }
    else                 { int rr = r-2064384; int n = rr>>9, k = rr&511; v = whh2[((size_t)n<<9)+k]; }
    u16 l0 = f2bf(v);
    float r1 = v - bf2f(l0); u16 l1 = f2bf(r1);
    float r2 = r1 - bf2f(l1); u16 l2 = f2bf(r2);
    wp[i] = l0; wp[P_W + i] = l1; wp[2*P_W + i] = l2;
  }
  for (int i = i0; i < 524288; i += stride){
    int c = i & 15, r = i >> 4, b = r & 511, tt = r >> 9;
    float v = (c < 9) ? skel[((size_t)b*64 + tt)*9 + c] : 0.f;
    skh[i] = f2bf(v);
  }
  for (int i = i0; i < 524288; i += stride) logacc[i] = 0.f;
  for (int i = i0; i < 272; i += stride) flg[i] = 0u;
}

// ---------------- h0: h1a f32 + 3 limb planes ----------------
__global__ __launch_bounds__(256) void k_h0(
    const float* __restrict__ se, const float* __restrict__ w, const float* __restrict__ bias,
    float* __restrict__ ws)
{
  float* h1af = ws + WOFF_HF;                 // state 0
  u16* hpl = (u16*)(ws + WOFF_HPL);           // state 0 limbs at +0
  int b = blockIdx.x, tid = threadIdx.x;
  __shared__ float ssh[HID];
  for (int i = tid; i < HID; i += 256) ssh[i] = se[b*HID + i];
  __syncthreads();
  for (int j = tid; j < HID; j += 256){
    float acc = 0.f;
    for (int q = 0; q < HID; q++) acc += ssh[q]*w[j*HID + q];
    float v = acc + bias[j];
    h1af[(size_t)b*512 + j] = v;
    u16 l0 = f2bf(v);
    float r1 = v - bf2f(l0); u16 l1 = f2bf(r1);
    float r2 = r1 - bf2f(l1); u16 l2 = f2bf(r2);
    hpl[(size_t)b*512 + j] = l0;
    hpl[262144 + (size_t)b*512 + j] = l1;
    hpl[524288 + (size_t)b*512 + j] = l2;
  }
}

// ---------------- persistent MFMA recurrence (3-limb bf16 split-6) ----------------
// grid 256 = 16 bg (32 batch) x 16 nstrip (32 hcols); 384 thr = 6 waves.
// wave w: gate g = w>>1, m-half mh = w&1; computes 2 n-tiles, 6 MFMAs each per window.
// bg-local flag barrier (16 strips), h-state f32+3 limb planes via agent sc1.
__global__ __launch_bounds__(384, 1) void k_persist(
    float* __restrict__ ws,
    const float* __restrict__ bih1, const float* __restrict__ bhh1,
    const float* __restrict__ bih2, const float* __restrict__ bhh2,
    const float* __restrict__ nfw,  const float* __restrict__ nfb,
    float* __restrict__ dout)
{
  const int tid = threadIdx.x;
  const int wvid = __builtin_amdgcn_readfirstlane(tid >> 6);
  const int g = wvid >> 1;
  const int mh = wvid & 1;
  const int lane = tid & 63;
  const int mloc = lane & 15;
  const int q8 = (lane >> 4) * 8;
  const int q4 = (lane >> 4) * 4;
  const int bg = blockIdx.x & 15;
  const int nstrip = blockIdx.x >> 4;
  const int b0 = bg * 32;
  const int n0 = nstrip * 32;

  u16* wp = (u16*)ws;
  const u16* skh = (const u16*)(ws + WOFF_SKH);
  u16* hpl = (u16*)(ws + WOFF_HPL);
  float* hf = ws + WOFF_HF;
  float* logacc = ws + WOFF_LOG;
  u32* flg = (u32*)(ws + WOFF_FLG);
  u32* go = flg + 256;
  const u16* xh = (const u16*)(ws + WOFF_XH);
  const u16* xl = xh + 8388608;

  __shared__ u16 Abuf[2][3][32][40];       // [buf][limb][b][k+pad]     15,360 B
  __shared__ u16 Wbuf[2][3][3][32][40];    // [buf][gate][limb][n][k+pad] 46,080 B
  __shared__ float eg[2][3][32][32];       // [ih/hh][gate][b][n]       24,576 B
  __shared__ float h2loc[32][32];          //                            4,096 B
  __shared__ u16 out_sh[32][12];

  u32 token = 0;
  int t = 0;

  auto gbar = [&](){
    __syncthreads();
    if (tid == 0){
      __hip_atomic_store(&flg[bg*16 + nstrip], token, __ATOMIC_RELEASE, __HIP_MEMORY_SCOPE_AGENT);
      if (nstrip == 0){
        for (int j = 1; j < 16; j++)
          while (ldu32(&flg[bg*16 + j]) < token) __builtin_amdgcn_s_sleep(4);
        __hip_atomic_store(&go[bg], token, __ATOMIC_RELEASE, __HIP_MEMORY_SCOPE_AGENT);
      } else {
        while (ldu32(&go[bg]) < token) __builtin_amdgcn_s_sleep(4);
      }
    }
    __syncthreads();
  };

  // ---- stage 32-k window of cat input (3 limbs; limb2 = 0) ----
  auto stageA_cat = [&](int buf, int kc){
    for (int idx = tid; idx < 3072; idx += 384){
      int p = idx >> 10, r = idx & 1023, bi = r >> 5, kk = r & 31, kg = kc + kk;
      u16 v = 0;
      if (p == 0){
        if (kg < 9)        v = out_sh[bi][kg];
        else if (kg < 265) v = xh[((size_t)t*512 + b0 + bi)*256 + kg - 9];
        else if (kg < 274) v = skh[((size_t)t*512 + b0 + bi)*16 + kg - 265];
      } else if (p == 1){
        if (kg >= 9 && kg < 265) v = xl[((size_t)t*512 + b0 + bi)*256 + kg - 9];
      }
      Abuf[buf][p][bi][kk] = v;
    }
  };
  // ---- stage 32-k window of h-state (3 limb planes, u32 pairs) ----
  auto stageA_h = [&](int buf, const u16* hb, int kc){
    for (int idx = tid; idx < 1536; idx += 384){
      int p = idx >> 9, r = idx & 511, bi = r >> 4, kp = r & 15;
      const u16* src = hb + (size_t)p*262144 + (size_t)(b0 + bi)*512 + kc + kp*2;
      u32 v = ldu32((const u32*)src);
      *(u32*)&Abuf[buf][p][bi][kp*2] = v;
    }
  };
  // ---- stage W window: 3 gates x 3 limbs x 32 n x 32 k ----
  auto stageW = [&](int buf, int SUB, int Kp, int kc){
    for (int idx = tid; idx < 1152; idx += 384){
      int gg = idx / 384, rem = idx % 384, p = rem >> 7, r2 = rem & 127, nn = r2 >> 2, c4 = r2 & 3;
      const u16* src = wp + (size_t)p*P_W + SUB + ((size_t)(gg*512 + n0 + nn))*Kp + kc + c4*8;
      short8 v = *(const short8*)src;
      *(short8*)&Wbuf[buf][gg][p][nn][c4*8] = v;
    }
  };
  // ---- compute: 2 n-tiles x 6 limb-MFMAs ----
  auto compute = [&](int buf, f32x4* acc){
    short8 a0 = *(const short8*)&Abuf[buf][0][mh*16 + mloc][q8];
    short8 a1 = *(const short8*)&Abuf[buf][1][mh*16 + mloc][q8];
    short8 a2 = *(const short8*)&Abuf[buf][2][mh*16 + mloc][q8];
    #pragma unroll
    for (int j = 0; j < 2; j++){
      short8 w0 = *(const short8*)&Wbuf[buf][g][0][j*16 + mloc][q8];
      short8 w1 = *(const short8*)&Wbuf[buf][g][1][j*16 + mloc][q8];
      short8 w2 = *(const short8*)&Wbuf[buf][g][2][j*16 + mloc][q8];
      acc[j] = MFMA16(a0, w0, acc[j], 0, 0, 0);
      acc[j] = MFMA16(a0, w1, acc[j], 0, 0, 0);
      acc[j] = MFMA16(a1, w0, acc[j], 0, 0, 0);
      acc[j] = MFMA16(a0, w2, acc[j], 0, 0, 0);
      acc[j] = MFMA16(a2, w0, acc[j], 0, 0, 0);
      acc[j] = MFMA16(a1, w1, acc[j], 0, 0, 0);
    }
  };
  auto run_phase = [&](int NW, int Kp, int SUB, int mode, const u16* hb, f32x4* acc){
    if (mode == 0) stageA_cat(0, 0); else stageA_h(0, hb, 0);
    stageW(0, SUB, Kp, 0);
    __syncthreads();
    for (int w = 0; w < NW; w++){
      if (w + 1 < NW){
        if (mode == 0) stageA_cat((w+1)&1, (w+1)*32); else stageA_h((w+1)&1, hb, (w+1)*32);
        stageW((w+1)&1, SUB, Kp, (w+1)*32);
      }
      compute(w & 1, acc);
      __syncthreads();
    }
  };

  auto epilogue = [&](const float* bih, const float* bhh,
                      const float* hpf, float* hnf, u16* hnl,
                      bool cell2, f32x4* accI, f32x4* accH){
    #pragma unroll
    for (int j = 0; j < 2; j++)
      #pragma unroll
      for (int i = 0; i < 4; i++){
        eg[0][g][mh*16 + q4 + i][j*16 + mloc] = accI[j][i];
        eg[1][g][mh*16 + q4 + i][j*16 + mloc] = accH[j][i];
      }
    __syncthreads();
    for (int e = tid; e < 1024; e += 384){
      int bi = e >> 5, nl = e & 31, n = n0 + nl, b = b0 + bi;
      float r  = 1.f/(1.f + expf(-(eg[0][0][bi][nl] + bih[n] + eg[1][0][bi][nl] + bhh[n])));
      float z  = 1.f/(1.f + expf(-(eg[0][1][bi][nl] + bih[512+n] + eg[1][1][bi][nl] + bhh[512+n])));
      float nn = tanhf(eg[0][2][bi][nl] + bih[1024+n] + r*(eg[1][2][bi][nl] + bhh[1024+n]));
      float hp = ldf(&hpf[(size_t)b*512 + n]);
      float h = (1.f - z)*nn + z*hp;
      stf(&hnf[(size_t)b*512 + n], h);
      u16 l0 = f2bf(h);
      float r1 = h - bf2f(l0); u16 l1 = f2bf(r1);
      float r2 = r1 - bf2f(l1); u16 l2 = f2bf(r2);
      sth(&hnl[(size_t)b*512 + n], l0);
      sth(&hnl[262144 + (size_t)b*512 + n], l1);
      sth(&hnl[524288 + (size_t)b*512 + n], l2);
      if (cell2) h2loc[bi][nl] = h;
    }
    __syncthreads();
    if (cell2){
      for (int e = tid; e < 288; e += 384){
        int c = e % 9, bi = e / 9;
        float s = 0.f;
        #pragma unroll
        for (int nl = 0; nl < 32; nl++) s += nfw[c*512 + n0 + nl]*h2loc[bi][nl];
        atomicAdd(&logacc[((size_t)t*512 + b0 + bi)*16 + c], s);
      }
    }
  };

  for (t = 0; t <= 64; t++){
    // state indices: h1a=0 h1b=1 h2a=2 h2b=3
    int s_h1p = (t & 1) ? 1 : 0, s_h1n = (t & 1) ? 0 : 1;
    int s_h2n = (t & 1) ? 3 : 2, s_h2p = (t & 1) ? 2 : 3;
    if (t == 0) s_h2p = s_h1n;
    const float* h1pf = hf + (size_t)s_h1p*262144;
    float*       h1nf = hf + (size_t)s_h1n*262144;
    const float* h2pf = hf + (size_t)s_h2p*262144;
    float*       h2nf = hf + (size_t)s_h2n*262144;
    const u16* h1pl = hpl + (size_t)s_h1p*786432;
    u16*       h1nl = hpl + (size_t)s_h1n*786432;
    const u16* h2pl = hpl + (size_t)s_h2p*786432;
    u16*       h2nl = hpl + (size_t)s_h2n*786432;

    token++; gbar();

    // ---- sample feedback from logacc[t-1] ----
    if (t > 0){
      for (int e = tid; e < 288; e += 384){
        int c = e % 9, bi = e / 9, b = b0 + bi;
        float lg = ldf(&logacc[((size_t)(t-1)*512 + b)*16 + c]) + nfb[c];
        if (nstrip == 0) dout[((size_t)b*64 + (t-1))*9 + c] = lg;
        if (t <= 63){
          u32 ka, kb; step_key(t-1, ka, kb);
          float rr = rng_uniform(ka, kb, (u32)(b*9 + c));
          float sg = 1.f/(1.f + expf(-lg));
          out_sh[bi][c] = (sg - rr > 0.f) ? (u16)0x3F80 : (u16)0;
        }
      }
    } else {
      for (int e = tid; e < 288; e += 384) out_sh[e/9][e%9] = 0;
    }
    __syncthreads();
    if (t == 64) break;

    // ---- GRU1: ih (cat, K=320) -> accI ; hh (h1prev, K=512) -> accH ----
    f32x4 accI[2] = {{0,0,0,0},{0,0,0,0}}, accH[2] = {{0,0,0,0},{0,0,0,0}};
    run_phase(10, 320, 0,       0, nullptr, accI);
    run_phase(16, 512, 491520,  1, h1pl,    accH);
    epilogue(bih1, bhh1, h1pf, h1nf, h1nl, false, accI, accH);

    token++; gbar();

    // ---- GRU2 ----
    f32x4 accI2[2] = {{0,0,0,0},{0,0,0,0}}, accH2[2] = {{0,0,0,0},{0,0,0,0}};
    run_phase(16, 512, 1277952, 1, h1nl, accI2);
    run_phase(16, 512, 2064384, 1, h2pl, accH2);
    epilogue(bih2, bhh2, h2pf, h2nf, h2nl, true, accI2, accH2);
  }
}

// ---------------- host ----------------
extern "C" void kernel_launch(void* const* d_in, const int* in_sizes, int n_in,
                              void* d_out, int out_size, void* d_ws, size_t ws_size,
                              hipStream_t stream) {
  (void)in_sizes; (void)n_in; (void)out_size; (void)ws_size;
  const float* z       = (const float*)d_in[0];
  const float* skel    = (const float*)d_in[2];
  const float* se      = (const float*)d_in[3];
  const float* ct1_w   = (const float*)d_in[6];
  const float* ct1_b   = (const float*)d_in[7];
  const float* bn1_g   = (const float*)d_in[8];
  const float* bn1_b   = (const float*)d_in[9];
  const float* bn1_m   = (const float*)d_in[10];
  const float* bn1_v   = (const float*)d_in[11];
  const float* ct2_w   = (const float*)d_in[12];
  const float* ct2_b   = (const float*)d_in[13];
  const float* bn2_g   = (const float*)d_in[14];
  const float* bn2_b   = (const float*)d_in[15];
  const float* bn2_m   = (const float*)d_in[16];
  const float* bn2_v   = (const float*)d_in[17];
  const float* hfc_w   = (const float*)d_in[18];
  const float* hfc_b   = (const float*)d_in[19];
  const float* g1_wih  = (const float*)d_in[20];
  const float* g1_whh  = (const float*)d_in[21];
  const float* g1_bih  = (const float*)d_in[22];
  const float* g1_bhh  = (const float*)d_in[23];
  const float* g2_wih  = (const float*)d_in[24];
  const float* g2_whh  = (const float*)d_in[25];
  const float* g2_bih  = (const float*)d_in[26];
  const float* g2_bhh  = (const float*)d_in[27];
  const float* nfc_w   = (const float*)d_in[28];
  const float* nfc_b   = (const float*)d_in[29];

  float* ws = (float*)d_ws;
  float* y1 = ws;                                  // conv intermediate (region reused by prep)
  u16* xh = (u16*)(ws + WOFF_XH);
  u16* xl = xh + 8388608;
  float* dout = (float*)d_out;

  k_conv1<<<dim3(L1, BATCH/8), 256, 0, stream>>>(z, ct1_w, ct1_b, bn1_g, bn1_b, bn1_m, bn1_v, y1);
  k_conv2<<<dim3(SLEN, BATCH/8), 256, 0, stream>>>(y1, ct2_w, ct2_b, bn2_g, bn2_b, bn2_m, bn2_v, xh, xl);
  k_prep<<<4096, 256, 0, stream>>>(g1_wih, g1_whh, g2_wih, g2_whh, skel, ws);
  k_h0<<<BATCH, 256, 0, stream>>>(se, hfc_w, hfc_b, ws);

  void* args[] = {
    (void*)&ws, (void*)&g1_bih, (void*)&g1_bhh, (void*)&g2_bih, (void*)&g2_bhh,
    (void*)&nfc_w, (void*)&nfc_b, (void*)&dout
  };
  hipLaunchCooperativeKernel((const void*)k_persist, dim3(256), dim3(384), args, 0, stream);
}